// Round 6
// baseline (3067.351 us; speedup 1.0000x reference)
//
#include <hip/hip_runtime.h>
#include <hip/hip_bf16.h>
#include <math.h>

// Problem dims
#define BB 32
#define TE 80
#define FEAT 4096
#define HH 256
#define W2V 256
#define TD 30
#define VV 32000
#define G4 1024   // 4*H

typedef unsigned short u16;
typedef unsigned int u32;
using f32x4 = __attribute__((ext_vector_type(4))) float;
using bf16x8 = __attribute__((ext_vector_type(8))) short;
using f16x2 = __attribute__((ext_vector_type(2))) _Float16;

__device__ __forceinline__ float sigm(float x) { return 1.0f / (1.0f + expf(-x)); }
__device__ __forceinline__ u16 f2bf(float f) {
  u32 u = __float_as_uint(f);
  u32 r = (u + 0x7FFFu + ((u >> 16) & 1u)) >> 16;
  return (u16)r;
}

#define AT_LOAD(p)     __hip_atomic_load((p), __ATOMIC_RELAXED, __HIP_MEMORY_SCOPE_AGENT)
#define AT_LOADF(p)    __hip_atomic_load((p), __ATOMIC_RELAXED, __HIP_MEMORY_SCOPE_AGENT)
#define AT_STORE(p, v) __hip_atomic_store((p), (v), __ATOMIC_RELAXED, __HIP_MEMORY_SCOPE_AGENT)

__device__ __forceinline__ float fdot2h(f16x2 a, f16x2 b, float c) {
#if __has_builtin(__builtin_amdgcn_fdot2)
  return __builtin_amdgcn_fdot2(a, b, c, false);
#else
  return c + (float)a[0] * (float)b[0] + (float)a[1] * (float)b[1];
#endif
}

// 256-element dot: w = 128 f16x2 register pairs, hS = LDS f16x2[128]
__device__ __forceinline__ float dot256(const f16x2 (&w)[128], const f16x2* hS) {
  const uint4* hv = (const uint4*)hS;
  float a = 0.f;
#pragma unroll
  for (int q = 0; q < 32; ++q) {
    uint4 u = hv[q];
    a = fdot2h(__builtin_bit_cast(f16x2, u.x), w[q * 4 + 0], a);
    a = fdot2h(__builtin_bit_cast(f16x2, u.y), w[q * 4 + 1], a);
    a = fdot2h(__builtin_bit_cast(f16x2, u.z), w[q * 4 + 2], a);
    a = fdot2h(__builtin_bit_cast(f16x2, u.w), w[q * 4 + 3], a);
  }
  return a;
}

// load one f32 weight row (256) into 128 f16x2 registers
__device__ __forceinline__ void load_wrow(f16x2 (&w)[128], const float* row) {
  const float4* r4 = (const float4*)row;
#pragma unroll
  for (int q = 0; q < 32; ++q) {
    float4 a = r4[2 * q];
    float4 b = r4[2 * q + 1];
    w[q * 4 + 0] = f16x2{(_Float16)a.x, (_Float16)a.y};
    w[q * 4 + 1] = f16x2{(_Float16)a.z, (_Float16)a.w};
    w[q * 4 + 2] = f16x2{(_Float16)b.x, (_Float16)b.y};
    w[q * 4 + 3] = f16x2{(_Float16)b.z, (_Float16)b.w};
  }
}

// ===========================================================================
// prep: all one-time elementwise work + argmax, one launch.
// blocks [0,4096) w_ih1->bf16 | [4096,8096) pack w_out | [8096,8352) w_ih2
// left->bf16 | [8352,8592) caption->bf16 | [8592,8600) init | [8600,9528) argmax
// ===========================================================================
__global__ __launch_bounds__(256) void prep_kernel(
    const float* __restrict__ w_ih1, const float* __restrict__ w_out,
    const float* __restrict__ w_ih2, const float* __restrict__ caption,
    const float* __restrict__ onehot,
    const float* __restrict__ b_ih1, const float* __restrict__ b_hh1,
    const float* __restrict__ b_ih2, const float* __restrict__ b_hh2,
    u16* __restrict__ w_ih1b, u16* __restrict__ wPK,
    u16* __restrict__ w_ih2lb, u16* __restrict__ capb,
    float* __restrict__ bias1, float* __restrict__ bias2,
    int* __restrict__ ctr, float* __restrict__ loss,
    int* __restrict__ targets) {
  int blk = blockIdx.x, tid = threadIdx.x;
  if (blk < 4096) {
    int i = blk * 256 + tid;  // < 1048576 float4s
    float4 v = *(const float4*)&w_ih1[(size_t)i * 4];
    *(ushort4*)&w_ih1b[(size_t)i * 4] =
        make_ushort4(f2bf(v.x), f2bf(v.y), f2bf(v.z), f2bf(v.w));
  } else if (blk < 8096) {
    int i = (blk - 4096) * 256 + tid;  // < 1,024,000  (n, kg)
    int n = i >> 5, kg = i & 31;
    float4 v0 = *(const float4*)&w_out[(size_t)n * 256 + kg * 8];
    float4 v1 = *(const float4*)&w_out[(size_t)n * 256 + kg * 8 + 4];
    size_t dst = ((size_t)((n >> 4) * 32 + kg) * 16 + (n & 15)) * 8;
    *(ushort4*)&wPK[dst] = make_ushort4(f2bf(v0.x), f2bf(v0.y), f2bf(v0.z), f2bf(v0.w));
    *(ushort4*)&wPK[dst + 4] = make_ushort4(f2bf(v1.x), f2bf(v1.y), f2bf(v1.z), f2bf(v1.w));
  } else if (blk < 8352) {
    int i = (blk - 8096) * 256 + tid;  // < 65536
    int row = i >> 6, c = i & 63;
    float4 v = *(const float4*)&w_ih2[(size_t)row * 512 + c * 4];
    *(ushort4*)&w_ih2lb[(size_t)row * 256 + c * 4] =
        make_ushort4(f2bf(v.x), f2bf(v.y), f2bf(v.z), f2bf(v.w));
  } else if (blk < 8592) {
    int i = (blk - 8352) * 256 + tid;  // < 61440
    float4 v = *(const float4*)&caption[(size_t)i * 4];
    *(ushort4*)&capb[(size_t)i * 4] =
        make_ushort4(f2bf(v.x), f2bf(v.y), f2bf(v.z), f2bf(v.w));
  } else if (blk < 8600) {
    int i = (blk - 8592) * 256 + tid;  // < 2048
    if (i < 1024) {
      bias1[i] = b_ih1[i] + b_hh1[i];
      bias2[i] = b_ih2[i] + b_hh2[i];
    }
    ctr[i] = 0;
    if (i == 0) *loss = 0.0f;
  } else {
    int k = blk - 8600;  // (s-1)*32 + b
    int s = (k >> 5) + 1, b = k & 31;
    const float* row = &onehot[((size_t)b * TD + s) * VV];
    float bv = -INFINITY;
    int bi = 0x7fffffff;
    for (int v = tid; v < VV; v += 256) {
      float x = row[v];
      if (x > bv || (x == bv && v < bi)) { bv = x; bi = v; }
    }
    __shared__ float sv[256];
    __shared__ int si[256];
    sv[tid] = bv; si[tid] = bi;
    __syncthreads();
    for (int off = 128; off; off >>= 1) {
      if (tid < off) {
        float ov = sv[tid + off]; int oi = si[tid + off];
        if (ov > sv[tid] || (ov == sv[tid] && oi < si[tid])) { sv[tid] = ov; si[tid] = oi; }
      }
      __syncthreads();
    }
    if (tid == 0) targets[k] = si[0];
  }
}

// ---------------------------------------------------------------------------
// MFMA GEMM: X1[r][n] = feat[r][:] . w_ih1b[n][:] + bias1[n]   (r = b*80+t)
#define GBM 128
#define GBN 128
#define GBK 64
#define LDSTR 72

__global__ __launch_bounds__(256) void gemm_x1_kernel(
    const float* __restrict__ A, const u16* __restrict__ Bw,
    const float* __restrict__ bias, float* __restrict__ C) {
  __shared__ __align__(16) u16 As[GBM * LDSTR];
  __shared__ __align__(16) u16 Bs[GBN * LDSTR];
  int tid = threadIdx.x;
  int rBase = blockIdx.y * GBM;
  int nBase = blockIdx.x * GBN;
  int lane = tid & 63, w = tid >> 6;
  int wrow = (w >> 1) * 64, wcol = (w & 1) * 64;
  int lrow = lane & 15, lk = (lane >> 4) * 8;

  f32x4 acc[4][4];
#pragma unroll
  for (int m = 0; m < 4; ++m)
#pragma unroll
    for (int n = 0; n < 4; ++n) acc[m][n] = (f32x4){0.f, 0.f, 0.f, 0.f};

  for (int k0 = 0; k0 < FEAT; k0 += GBK) {
#pragma unroll
    for (int i = 0; i < 8; ++i) {
      int f = i * 256 + tid;
      int r = f >> 4, c = (f & 15) << 2;
      float4 v = *(const float4*)&A[(size_t)(rBase + r) * FEAT + k0 + c];
      *(ushort4*)&As[r * LDSTR + c] =
          make_ushort4(f2bf(v.x), f2bf(v.y), f2bf(v.z), f2bf(v.w));
    }
#pragma unroll
    for (int i = 0; i < 4; ++i) {
      int f = i * 256 + tid;
      int r = f >> 3, c = (f & 7) << 3;
      uint4 v = *(const uint4*)&Bw[(size_t)(nBase + r) * FEAT + k0 + c];
      *(uint4*)&Bs[r * LDSTR + c] = v;
    }
    __syncthreads();
    bf16x8 af[4][2], bfr[4][2];
#pragma unroll
    for (int m = 0; m < 4; ++m)
#pragma unroll
      for (int s2 = 0; s2 < 2; ++s2)
        af[m][s2] = *(const bf16x8*)&As[(wrow + m * 16 + lrow) * LDSTR + s2 * 32 + lk];
#pragma unroll
    for (int n = 0; n < 4; ++n)
#pragma unroll
      for (int s2 = 0; s2 < 2; ++s2)
        bfr[n][s2] = *(const bf16x8*)&Bs[(wcol + n * 16 + lrow) * LDSTR + s2 * 32 + lk];
#pragma unroll
    for (int s2 = 0; s2 < 2; ++s2)
#pragma unroll
      for (int m = 0; m < 4; ++m)
#pragma unroll
        for (int n = 0; n < 4; ++n)
          acc[m][n] = __builtin_amdgcn_mfma_f32_16x16x32_bf16(
              af[m][s2], bfr[n][s2], acc[m][n], 0, 0, 0);
    __syncthreads();
  }
  int orow = (lane >> 4) * 4;
  int ocol = lane & 15;
#pragma unroll
  for (int m = 0; m < 4; ++m)
#pragma unroll
    for (int n = 0; n < 4; ++n) {
      int cidx = nBase + wcol + n * 16 + ocol;
      float bv = bias[cidx];
#pragma unroll
      for (int q = 0; q < 4; ++q) {
        int r = rBase + wrow + m * 16 + orow + q;
        C[(size_t)r * G4 + cidx] = acc[m][n][q] + bv;
      }
    }
}

// ---------------------------------------------------------------------------
// MFMA xw2: XW2[(t*32+b)][n] = capb[b][t][:] . w_ih2lb[n][:] + bias2[n]
__global__ __launch_bounds__(256) void xw2_mfma_kernel(
    const u16* __restrict__ capb, const u16* __restrict__ w_ih2lb,
    const float* __restrict__ bias2, float* __restrict__ XW2) {
  __shared__ __align__(16) u16 As[32 * 264];
  __shared__ __align__(16) u16 Bs[64 * 264];
  int tid = threadIdx.x;
  int nBase = blockIdx.x * 64;
  int t = blockIdx.y;
#pragma unroll
  for (int it = 0; it < 4; ++it) {
    int i = it * 256 + tid;
    int r = i >> 5, c8 = i & 31;
    *(uint4*)&As[r * 264 + c8 * 8] =
        *(const uint4*)&capb[((size_t)r * TD + t) * 256 + c8 * 8];
  }
#pragma unroll
  for (int it = 0; it < 8; ++it) {
    int i = it * 256 + tid;
    int r = i >> 5, c8 = i & 31;
    *(uint4*)&Bs[r * 264 + c8 * 8] =
        *(const uint4*)&w_ih2lb[(size_t)(nBase + r) * 256 + c8 * 8];
  }
  __syncthreads();
  int lane = tid & 63, w = tid >> 6;
  int lrow = lane & 15, lk = (lane >> 4) * 8;
  f32x4 acc[2];
  acc[0] = (f32x4){0.f, 0.f, 0.f, 0.f};
  acc[1] = (f32x4){0.f, 0.f, 0.f, 0.f};
#pragma unroll
  for (int ks = 0; ks < 8; ++ks) {
    bf16x8 bfr = *(const bf16x8*)&Bs[(w * 16 + lrow) * 264 + ks * 32 + lk];
#pragma unroll
    for (int m = 0; m < 2; ++m) {
      bf16x8 af = *(const bf16x8*)&As[(m * 16 + lrow) * 264 + ks * 32 + lk];
      acc[m] = __builtin_amdgcn_mfma_f32_16x16x32_bf16(af, bfr, acc[m], 0, 0, 0);
    }
  }
  int col = nBase + w * 16 + (lane & 15);
  float bv = bias2[col];
  int orow = (lane >> 4) * 4;
#pragma unroll
  for (int m = 0; m < 2; ++m)
#pragma unroll
    for (int q = 0; q < 4; ++q) {
      int bb = m * 16 + orow + q;
      XW2[((size_t)t * 32 + bb) * G4 + col] = acc[m][q] + bv;
    }
}

// ===========================================================================
// Persistent recurrent kernel. 64 blocks x 1024 threads (cooperative).
// blocks [0,32): L1 role (batch b): lstm1 chain + A2[t] = w_ih2r.h1[t] + x2,
//   all in-block (h1 in LDS, c1 in regs, weights in f16 regs). Fire-and-
//   forget A2 stores + per-batch counter.
// blocks [32,64): L2B role (batch b): gates2 = A2[t] + w_hh2.h2, h2/c2 and
//   encoder h2 history (attention) all in LDS. Waits only on A2 counter
//   (producer runs ahead -> amortized).
// ===========================================================================
struct PP {
  const float *X1, *XW2, *bias1, *bias2;
  const float *w_hh1, *w_ih2, *w_hh2;
  float* A2;    // [109][32][1024]
  u16* H2NB;    // [29][32][256] bf16
  int* ctr;     // ctr[b*32]
};

__global__ __launch_bounds__(1024, 1) void recurrent_kernel(PP p) {
  __shared__ __align__(16) f16x2 hS[128];     // h state (f16 pairs)
  __shared__ float gS[1024];
  __shared__ float hF[256];
  __shared__ float encL[TE * 257];            // L2B: encoder h2 history
  __shared__ float ps[320];
  __shared__ float sc[88];
  int bid = blockIdx.x, tid = threadIdx.x;
  bool isL1 = bid < 32;
  int b = isL1 ? bid : bid - 32;
  int j = tid;
  float creg = 0.f;
  if (tid < 128) hS[tid] = f16x2{(_Float16)0.f, (_Float16)0.f};

  if (isL1) {
    f16x2 wA[128], wB[128];
    load_wrow(wA, p.w_hh1 + (size_t)j * 256);
    load_wrow(wB, p.w_ih2 + (size_t)j * 512 + 256);
    float b1j = p.bias1[j];
    float b2j = p.bias2[j];
    int* myctr = p.ctr + b * 32;
    __syncthreads();
    for (int T = 0; T < 109; ++T) {
      float x1v = (T < TE) ? p.X1[((size_t)b * TE + T) * G4 + j] : b1j;
      float x2v = (T < TE) ? b2j : p.XW2[((size_t)(T - TE) * 32 + b) * G4 + j];
      float a = dot256(wA, hS);
      gS[j] = a + x1v;
      __syncthreads();
      if (tid < 256) {
        float gi = gS[tid], gf = gS[256 + tid], gg = gS[512 + tid], go = gS[768 + tid];
        creg = sigm(gf) * creg + sigm(gi) * tanhf(gg);
        hF[tid] = sigm(go) * tanhf(creg);
      }
      __syncthreads();
      if (tid < 128) hS[tid] = f16x2{(_Float16)hF[2 * tid], (_Float16)hF[2 * tid + 1]};
      __syncthreads();
      float a2 = dot256(wB, hS) + x2v;
      AT_STORE(&p.A2[((size_t)T * 32 + b) * G4 + j], a2);
      asm volatile("s_waitcnt vmcnt(0)" ::: "memory");
      __syncthreads();
      if (tid == 0)
        __hip_atomic_fetch_add(myctr, 1, __ATOMIC_RELAXED, __HIP_MEMORY_SCOPE_AGENT);
    }
  } else {
    f16x2 wA[128];
    load_wrow(wA, p.w_hh2 + (size_t)j * 256);
    int* myctr = p.ctr + b * 32;
    int seen = 0;
    __syncthreads();
    for (int U = 0; U < 109; ++U) {
      if (tid == 0 && seen < U + 1) {
        int guard = 0, v;
        do {
          v = AT_LOAD(myctr);
          if (v >= U + 1) break;
          __builtin_amdgcn_s_sleep(2);
        } while (++guard < (1 << 22));
        // one acquire to order subsequent data reads after observed count
        (void)__hip_atomic_load(myctr, __ATOMIC_ACQUIRE, __HIP_MEMORY_SCOPE_AGENT);
        seen = v;
      }
      __syncthreads();
      float a2 = AT_LOADF(&p.A2[((size_t)U * 32 + b) * G4 + j]);
      float g2 = dot256(wA, hS);
      gS[j] = a2 + g2;
      __syncthreads();
      if (tid < 256) {
        float gi = gS[tid], gf = gS[256 + tid], gg = gS[512 + tid], go = gS[768 + tid];
        creg = sigm(gf) * creg + sigm(gi) * tanhf(gg);
        float h = sigm(go) * tanhf(creg);
        hF[tid] = h;
        if (U < TE) encL[U * 257 + tid] = h;
        else p.H2NB[((size_t)(U - TE) * 32 + b) * 256 + tid] = f2bf(h);
      }
      __syncthreads();
      if (U < TE) {
        if (tid < 128) hS[tid] = f16x2{(_Float16)hF[2 * tid], (_Float16)hF[2 * tid + 1]};
      } else if (U < 108) {
        // attention: q = hF (h2n); scores over encL; ctx -> next h2
        if (tid < 320) {
          int t4 = tid >> 2, kq = tid & 3;
          const float* e = &encL[t4 * 257 + kq * 64];
          const float* qq = &hF[kq * 64];
          float a = 0.f;
#pragma unroll 8
          for (int k2 = 0; k2 < 64; ++k2) a += e[k2] * qq[k2];
          ps[tid] = a;
        }
        __syncthreads();
        if (tid == 0) {
          float m = -INFINITY;
          for (int t2 = 0; t2 < TE; ++t2) {
            float s4 = ps[4 * t2] + ps[4 * t2 + 1] + ps[4 * t2 + 2] + ps[4 * t2 + 3];
            sc[t2] = s4;
            m = fmaxf(m, s4);
          }
          float s = 0.f;
          for (int t2 = 0; t2 < TE; ++t2) { sc[t2] = expf(sc[t2] - m); s += sc[t2]; }
          sc[84] = 1.0f / s;
        }
        __syncthreads();
        if (tid < 256) {
          float inv = sc[84];
          float a = 0.f;
          for (int t2 = 0; t2 < TE; ++t2) a += sc[t2] * encL[t2 * 257 + tid];
          hF[tid] = a * inv;
        }
        __syncthreads();
        if (tid < 128) hS[tid] = f16x2{(_Float16)hF[2 * tid], (_Float16)hF[2 * tid + 1]};
      }
      __syncthreads();
    }
  }
}

// ===========================================================================
// Batched logits + fused CE partials: M=928, N=32000, K=256; A = H2NB bf16.
// ===========================================================================
__global__ __launch_bounds__(256, 1) void logits_ce_kernel(
    const u16* __restrict__ H2NB, const u16* __restrict__ wPK,
    const float* __restrict__ b_out, const int* __restrict__ targets,
    float* __restrict__ pmaxA, float* __restrict__ psumA,
    float* __restrict__ tgtv) {
  __shared__ __align__(16) u16 bS[32768];
  __shared__ __align__(16) u16 aS[32 * 264];
  __shared__ int tS[32];
  int tid = threadIdx.x, bid = blockIdx.x;
  const u16* src = wPK + (size_t)bid * 32768;
  for (int i = tid; i < 4096; i += 256)
    *(uint4*)&bS[i * 8] = *(const uint4*)&src[i * 8];
  int wid = tid >> 6, lane = tid & 63, lcol = lane & 15, lk = lane >> 4;
  float bo[2];
#pragma unroll
  for (int n = 0; n < 2; ++n) bo[n] = b_out[(bid * 8 + wid * 2 + n) * 16 + lcol];

  for (int rg = 0; rg < 29; ++rg) {
    __syncthreads();
    for (int i = tid; i < 1024; i += 256) {
      int r = i >> 5, c8 = i & 31;
      *(uint4*)&aS[r * 264 + c8 * 8] =
          *(const uint4*)&H2NB[(size_t)rg * 8192 + r * 256 + c8 * 8];
    }
    if (tid < 32) tS[tid] = targets[rg * 32 + tid];
    __syncthreads();
    f32x4 acc[2][2];
#pragma unroll
    for (int m = 0; m < 2; ++m)
#pragma unroll
      for (int n = 0; n < 2; ++n) acc[m][n] = (f32x4){0.f, 0.f, 0.f, 0.f};
#pragma unroll
    for (int ks = 0; ks < 8; ++ks) {
      bf16x8 a0 = *(const bf16x8*)&aS[lcol * 264 + ks * 32 + lk * 8];
      bf16x8 a1 = *(const bf16x8*)&aS[(16 + lcol) * 264 + ks * 32 + lk * 8];
      bf16x8 b0 = *(const bf16x8*)&bS[(wid * 2) * 4096 + ((ks * 4 + lk) * 16 + lcol) * 8];
      bf16x8 b1 = *(const bf16x8*)&bS[(wid * 2 + 1) * 4096 + ((ks * 4 + lk) * 16 + lcol) * 8];
      acc[0][0] = __builtin_amdgcn_mfma_f32_16x16x32_bf16(a0, b0, acc[0][0], 0, 0, 0);
      acc[0][1] = __builtin_amdgcn_mfma_f32_16x16x32_bf16(a0, b1, acc[0][1], 0, 0, 0);
      acc[1][0] = __builtin_amdgcn_mfma_f32_16x16x32_bf16(a1, b0, acc[1][0], 0, 0, 0);
      acc[1][1] = __builtin_amdgcn_mfma_f32_16x16x32_bf16(a1, b1, acc[1][1], 0, 0, 0);
    }
    int nbase = (bid * 8 + wid * 2) * 16 + lcol;
#pragma unroll
    for (int m = 0; m < 2; ++m) {
      float pm[4], psv[4];
#pragma unroll
      for (int q = 0; q < 4; ++q) {
        float v0 = acc[m][0][q] + bo[0];
        float v1 = acc[m][1][q] + bo[1];
        int r = m * 16 + lk * 4 + q;
        int tg = tS[r];
        if (tg == nbase) tgtv[rg * 32 + r] = v0;
        if (tg == nbase + 16) tgtv[rg * 32 + r] = v1;
        float mx = fmaxf(v0, v1);
#pragma unroll
        for (int d = 1; d < 16; d <<= 1) mx = fmaxf(mx, __shfl_xor(mx, d));
        float e = expf(v0 - mx) + expf(v1 - mx);
#pragma unroll
        for (int d = 1; d < 16; d <<= 1) e += __shfl_xor(e, d);
        pm[q] = mx;
        psv[q] = e;
      }
      if (lcol == 0) {
        int chunk = bid * 4 + wid;
#pragma unroll
        for (int q = 0; q < 4; ++q) {
          int r2 = rg * 32 + m * 16 + lk * 4 + q;
          pmaxA[(size_t)r2 * 1000 + chunk] = pm[q];
          psumA[(size_t)r2 * 1000 + chunk] = psv[q];
        }
      }
    }
  }
}

// one block per row; reduce 1000 chunks
__global__ __launch_bounds__(256) void ce_final_kernel(
    const float* __restrict__ pmaxA, const float* __restrict__ psumA,
    const float* __restrict__ tgtv, float* __restrict__ loss) {
  int row = blockIdx.x;
  int tid = threadIdx.x;
  const float* pm = pmaxA + (size_t)row * 1000;
  const float* psv = psumA + (size_t)row * 1000;
  __shared__ float sm[256];
  float m = -INFINITY;
  for (int c = tid; c < 1000; c += 256) m = fmaxf(m, pm[c]);
  sm[tid] = m;
  __syncthreads();
  for (int off = 128; off; off >>= 1) {
    if (tid < off) sm[tid] = fmaxf(sm[tid], sm[tid + off]);
    __syncthreads();
  }
  float M = sm[0];
  __syncthreads();
  float s = 0.f;
  for (int c = tid; c < 1000; c += 256) s += psv[c] * expf(pm[c] - M);
  sm[tid] = s;
  __syncthreads();
  for (int off = 128; off; off >>= 1) {
    if (tid < off) sm[tid] += sm[tid + off];
    __syncthreads();
  }
  if (tid == 0)
    atomicAdd(loss, (M + logf(sm[0]) - tgtv[row]) * (1.0f / 1024.0f));
}

__global__ void finalize_kernel(const float* __restrict__ loss, float* __restrict__ out) {
  if (threadIdx.x == 0) out[0] = loss[0];
}

// ---------------------------------------------------------------------------
extern "C" void kernel_launch(void* const* d_in, const int* in_sizes, int n_in,
                              void* d_out, int out_size, void* d_ws, size_t ws_size,
                              hipStream_t stream) {
  (void)in_sizes; (void)n_in; (void)out_size; (void)ws_size;
  const float* feat    = (const float*)d_in[0];
  const float* caption = (const float*)d_in[1];
  const float* onehot  = (const float*)d_in[2];
  const float* w_ih1   = (const float*)d_in[4];
  const float* w_hh1   = (const float*)d_in[5];
  const float* b_ih1   = (const float*)d_in[6];
  const float* b_hh1   = (const float*)d_in[7];
  const float* w_ih2   = (const float*)d_in[8];
  const float* w_hh2   = (const float*)d_in[9];
  const float* b_ih2   = (const float*)d_in[10];
  const float* b_hh2   = (const float*)d_in[11];
  const float* w_out   = (const float*)d_in[12];
  const float* b_out   = (const float*)d_in[13];

  char* p = (char*)d_ws;
  auto alloc = [&](size_t bytes) {
    char* r = p;
    p += (bytes + 255) & ~(size_t)255;
    return r;
  };
  float* X1      = (float*)alloc(2560ull * 1024 * 4);      // 10.5 MB
  float* XW2     = (float*)alloc(29ull * 32 * 1024 * 4);   // 3.8 MB
  float* A2      = (float*)alloc(109ull * 32 * 1024 * 4);  // 14.3 MB
  float* bias1   = (float*)alloc(1024 * 4);
  float* bias2   = (float*)alloc(1024 * 4);
  int*   ctr     = (int*)alloc(2048 * 4);
  u16*   H2NB    = (u16*)alloc(29ull * 8192 * 2);
  float* pmaxA   = (float*)alloc(928ull * 1000 * 4);
  float* psumA   = (float*)alloc(928ull * 1000 * 4);
  float* tgtv    = (float*)alloc(928 * 4);
  float* lossacc = (float*)alloc(256);
  int*   targets = (int*)alloc(29 * 32 * 4);
  u16*   w_ih1b  = (u16*)alloc(1024ull * 4096 * 2);        // 8.4 MB
  u16*   w_ih2lb = (u16*)alloc(1024ull * 256 * 2);
  u16*   capb    = (u16*)alloc(32ull * 30 * 256 * 2);
  u16*   wPK     = (u16*)alloc(2000ull * 32 * 16 * 8 * 2); // 16.4 MB

  prep_kernel<<<9528, 256, 0, stream>>>(
      w_ih1, w_out, w_ih2, caption, onehot, b_ih1, b_hh1, b_ih2, b_hh2,
      w_ih1b, wPK, w_ih2lb, capb, bias1, bias2, ctr, lossacc, targets);
  gemm_x1_kernel<<<dim3(8, 20), 256, 0, stream>>>(feat, w_ih1b, bias1, X1);
  xw2_mfma_kernel<<<dim3(16, 29), 256, 0, stream>>>(capb, w_ih2lb, bias2, XW2);

  PP pp;
  pp.X1 = X1; pp.XW2 = XW2; pp.bias1 = bias1; pp.bias2 = bias2;
  pp.w_hh1 = w_hh1; pp.w_ih2 = w_ih2; pp.w_hh2 = w_hh2;
  pp.A2 = A2; pp.H2NB = H2NB; pp.ctr = ctr;
  void* args[] = {&pp};
  hipLaunchCooperativeKernel((const void*)recurrent_kernel, dim3(64), dim3(1024),
                             args, 0, stream);

  logits_ce_kernel<<<250, 256, 0, stream>>>(H2NB, wPK, b_out, targets, pmaxA, psumA, tgtv);
  ce_final_kernel<<<928, 256, 0, stream>>>(pmaxA, psumA, tgtv, lossacc);
  finalize_kernel<<<1, 64, 0, stream>>>(lossacc, (float*)d_out);
}

// Round 7
// 1496.524 us; speedup vs baseline: 2.0497x; 2.0497x over previous
//
#include <hip/hip_runtime.h>
#include <hip/hip_bf16.h>
#include <math.h>

// Problem dims
#define BB 32
#define TE 80
#define FEAT 4096
#define HH 256
#define W2V 256
#define TD 30
#define VV 32000
#define G4 1024   // 4*H

typedef unsigned short u16;
typedef unsigned int u32;
using f32x4 = __attribute__((ext_vector_type(4))) float;
using bf16x8 = __attribute__((ext_vector_type(8))) short;
using f16x2 = __attribute__((ext_vector_type(2))) _Float16;

__device__ __forceinline__ float sigm(float x) { return 1.0f / (1.0f + expf(-x)); }
__device__ __forceinline__ u16 f2bf(float f) {
  u32 u = __float_as_uint(f);
  u32 r = (u + 0x7FFFu + ((u >> 16) & 1u)) >> 16;
  return (u16)r;
}
__device__ __forceinline__ u16 f2h(float f) {
  return __builtin_bit_cast(u16, (_Float16)f);
}

#define AT_LOAD(p)     __hip_atomic_load((p), __ATOMIC_RELAXED, __HIP_MEMORY_SCOPE_AGENT)
#define AT_STORE(p, v) __hip_atomic_store((p), (v), __ATOMIC_RELAXED, __HIP_MEMORY_SCOPE_AGENT)

__device__ __forceinline__ float fdot2h(f16x2 a, f16x2 b, float c) {
#if __has_builtin(__builtin_amdgcn_fdot2)
  return __builtin_amdgcn_fdot2(a, b, c, false);
#else
  return c + (float)a[0] * (float)b[0] + (float)a[1] * (float)b[1];
#endif
}

// load one f16 weight row (256 f16 = 32 uint4) into 128 f16x2 registers
__device__ __forceinline__ void load_wrow16(f16x2 (&w)[128], const u16* row) {
  const uint4* r4 = (const uint4*)row;
#pragma unroll
  for (int q = 0; q < 32; ++q) {
    uint4 u = r4[q];
    w[q * 4 + 0] = __builtin_bit_cast(f16x2, u.x);
    w[q * 4 + 1] = __builtin_bit_cast(f16x2, u.y);
    w[q * 4 + 2] = __builtin_bit_cast(f16x2, u.z);
    w[q * 4 + 3] = __builtin_bit_cast(f16x2, u.w);
  }
}

// ===========================================================================
// prep: all one-time elementwise work + argmax, one launch.
// ===========================================================================
__global__ __launch_bounds__(256) void prep_kernel(
    const float* __restrict__ w_ih1, const float* __restrict__ w_out,
    const float* __restrict__ w_ih2, const float* __restrict__ caption,
    const float* __restrict__ onehot,
    const float* __restrict__ w_hh1, const float* __restrict__ w_hh2,
    const float* __restrict__ b_ih1, const float* __restrict__ b_hh1,
    const float* __restrict__ b_ih2, const float* __restrict__ b_hh2,
    u16* __restrict__ w_ih1b, u16* __restrict__ wPK,
    u16* __restrict__ w_ih2lb, u16* __restrict__ capb,
    u16* __restrict__ w_hh1h, u16* __restrict__ w_hh2h, u16* __restrict__ w_ih2rh,
    float* __restrict__ bias1, float* __restrict__ bias2,
    int* __restrict__ flags, float* __restrict__ loss,
    int* __restrict__ targets) {
  int blk = blockIdx.x, tid = threadIdx.x;
  if (blk < 4096) {
    int i = blk * 256 + tid;
    float4 v = *(const float4*)&w_ih1[(size_t)i * 4];
    *(ushort4*)&w_ih1b[(size_t)i * 4] =
        make_ushort4(f2bf(v.x), f2bf(v.y), f2bf(v.z), f2bf(v.w));
  } else if (blk < 8096) {
    int i = (blk - 4096) * 256 + tid;  // (n, kg)
    int n = i >> 5, kg = i & 31;
    float4 v0 = *(const float4*)&w_out[(size_t)n * 256 + kg * 8];
    float4 v1 = *(const float4*)&w_out[(size_t)n * 256 + kg * 8 + 4];
    size_t dst = ((size_t)((n >> 4) * 32 + kg) * 16 + (n & 15)) * 8;
    *(ushort4*)&wPK[dst] = make_ushort4(f2bf(v0.x), f2bf(v0.y), f2bf(v0.z), f2bf(v0.w));
    *(ushort4*)&wPK[dst + 4] = make_ushort4(f2bf(v1.x), f2bf(v1.y), f2bf(v1.z), f2bf(v1.w));
  } else if (blk < 8352) {
    int i = (blk - 8096) * 256 + tid;
    int row = i >> 6, c = i & 63;
    float4 v = *(const float4*)&w_ih2[(size_t)row * 512 + c * 4];
    *(ushort4*)&w_ih2lb[(size_t)row * 256 + c * 4] =
        make_ushort4(f2bf(v.x), f2bf(v.y), f2bf(v.z), f2bf(v.w));
  } else if (blk < 8592) {
    int i = (blk - 8352) * 256 + tid;
    float4 v = *(const float4*)&caption[(size_t)i * 4];
    *(ushort4*)&capb[(size_t)i * 4] =
        make_ushort4(f2bf(v.x), f2bf(v.y), f2bf(v.z), f2bf(v.w));
  } else if (blk < 9033) {
    int i = (blk - 8592) * 256 + tid;
    if (i < 112640) flags[i] = 0;
    if (i < 1024) {
      bias1[i] = b_ih1[i] + b_hh1[i];
      bias2[i] = b_ih2[i] + b_hh2[i];
    }
    if (i == 0) *loss = 0.0f;
  } else if (blk < 9289) {
    int i = (blk - 9033) * 256 + tid;  // w_hh1 -> f16, 65536 float4s
    float4 v = *(const float4*)&w_hh1[(size_t)i * 4];
    *(ushort4*)&w_hh1h[(size_t)i * 4] =
        make_ushort4(f2h(v.x), f2h(v.y), f2h(v.z), f2h(v.w));
  } else if (blk < 9545) {
    int i = (blk - 9289) * 256 + tid;  // w_hh2 -> f16
    float4 v = *(const float4*)&w_hh2[(size_t)i * 4];
    *(ushort4*)&w_hh2h[(size_t)i * 4] =
        make_ushort4(f2h(v.x), f2h(v.y), f2h(v.z), f2h(v.w));
  } else if (blk < 9801) {
    int i = (blk - 9545) * 256 + tid;  // w_ih2[:,256:512] -> f16
    int row = i >> 6, c = i & 63;
    float4 v = *(const float4*)&w_ih2[(size_t)row * 512 + 256 + c * 4];
    *(ushort4*)&w_ih2rh[(size_t)row * 256 + c * 4] =
        make_ushort4(f2h(v.x), f2h(v.y), f2h(v.z), f2h(v.w));
  } else {
    int k = blk - 9801;  // (s-1)*32 + b
    int s = (k >> 5) + 1, b = k & 31;
    const float* row = &onehot[((size_t)b * TD + s) * VV];
    float bv = -INFINITY;
    int bi = 0x7fffffff;
    for (int v = tid; v < VV; v += 256) {
      float x = row[v];
      if (x > bv || (x == bv && v < bi)) { bv = x; bi = v; }
    }
    __shared__ float sv[256];
    __shared__ int si[256];
    sv[tid] = bv; si[tid] = bi;
    __syncthreads();
    for (int off = 128; off; off >>= 1) {
      if (tid < off) {
        float ov = sv[tid + off]; int oi = si[tid + off];
        if (ov > sv[tid] || (ov == sv[tid] && oi < si[tid])) { sv[tid] = ov; si[tid] = oi; }
      }
      __syncthreads();
    }
    if (tid == 0) targets[k] = si[0];
  }
}

// ---------------------------------------------------------------------------
// MFMA GEMM: X1[r][n] = feat[r][:] . w_ih1b[n][:] + bias1[n]   (r = b*80+t)
#define GBM 128
#define GBN 128
#define GBK 64
#define LDSTR 72

__global__ __launch_bounds__(256) void gemm_x1_kernel(
    const float* __restrict__ A, const u16* __restrict__ Bw,
    const float* __restrict__ bias, float* __restrict__ C) {
  __shared__ __align__(16) u16 As[GBM * LDSTR];
  __shared__ __align__(16) u16 Bs[GBN * LDSTR];
  int tid = threadIdx.x;
  int rBase = blockIdx.y * GBM;
  int nBase = blockIdx.x * GBN;
  int lane = tid & 63, w = tid >> 6;
  int wrow = (w >> 1) * 64, wcol = (w & 1) * 64;
  int lrow = lane & 15, lk = (lane >> 4) * 8;

  f32x4 acc[4][4];
#pragma unroll
  for (int m = 0; m < 4; ++m)
#pragma unroll
    for (int n = 0; n < 4; ++n) acc[m][n] = (f32x4){0.f, 0.f, 0.f, 0.f};

  for (int k0 = 0; k0 < FEAT; k0 += GBK) {
#pragma unroll
    for (int i = 0; i < 8; ++i) {
      int f = i * 256 + tid;
      int r = f >> 4, c = (f & 15) << 2;
      float4 v = *(const float4*)&A[(size_t)(rBase + r) * FEAT + k0 + c];
      *(ushort4*)&As[r * LDSTR + c] =
          make_ushort4(f2bf(v.x), f2bf(v.y), f2bf(v.z), f2bf(v.w));
    }
#pragma unroll
    for (int i = 0; i < 4; ++i) {
      int f = i * 256 + tid;
      int r = f >> 3, c = (f & 7) << 3;
      uint4 v = *(const uint4*)&Bw[(size_t)(nBase + r) * FEAT + k0 + c];
      *(uint4*)&Bs[r * LDSTR + c] = v;
    }
    __syncthreads();
    bf16x8 af[4][2], bfr[4][2];
#pragma unroll
    for (int m = 0; m < 4; ++m)
#pragma unroll
      for (int s2 = 0; s2 < 2; ++s2)
        af[m][s2] = *(const bf16x8*)&As[(wrow + m * 16 + lrow) * LDSTR + s2 * 32 + lk];
#pragma unroll
    for (int n = 0; n < 4; ++n)
#pragma unroll
      for (int s2 = 0; s2 < 2; ++s2)
        bfr[n][s2] = *(const bf16x8*)&Bs[(wcol + n * 16 + lrow) * LDSTR + s2 * 32 + lk];
#pragma unroll
    for (int s2 = 0; s2 < 2; ++s2)
#pragma unroll
      for (int m = 0; m < 4; ++m)
#pragma unroll
        for (int n = 0; n < 4; ++n)
          acc[m][n] = __builtin_amdgcn_mfma_f32_16x16x32_bf16(
              af[m][s2], bfr[n][s2], acc[m][n], 0, 0, 0);
    __syncthreads();
  }
  int orow = (lane >> 4) * 4;
  int ocol = lane & 15;
#pragma unroll
  for (int m = 0; m < 4; ++m)
#pragma unroll
    for (int n = 0; n < 4; ++n) {
      int cidx = nBase + wcol + n * 16 + ocol;
      float bv = bias[cidx];
#pragma unroll
      for (int q = 0; q < 4; ++q) {
        int r = rBase + wrow + m * 16 + orow + q;
        C[(size_t)r * G4 + cidx] = acc[m][n][q] + bv;
      }
    }
}

// ---------------------------------------------------------------------------
// MFMA xw2: XW2[(t*32+b)][n] = capb[b][t][:] . w_ih2lb[n][:] + bias2[n]
__global__ __launch_bounds__(256) void xw2_mfma_kernel(
    const u16* __restrict__ capb, const u16* __restrict__ w_ih2lb,
    const float* __restrict__ bias2, float* __restrict__ XW2) {
  __shared__ __align__(16) u16 As[32 * 264];
  __shared__ __align__(16) u16 Bs[64 * 264];
  int tid = threadIdx.x;
  int nBase = blockIdx.x * 64;
  int t = blockIdx.y;
#pragma unroll
  for (int it = 0; it < 4; ++it) {
    int i = it * 256 + tid;
    int r = i >> 5, c8 = i & 31;
    *(uint4*)&As[r * 264 + c8 * 8] =
        *(const uint4*)&capb[((size_t)r * TD + t) * 256 + c8 * 8];
  }
#pragma unroll
  for (int it = 0; it < 8; ++it) {
    int i = it * 256 + tid;
    int r = i >> 5, c8 = i & 31;
    *(uint4*)&Bs[r * 264 + c8 * 8] =
        *(const uint4*)&w_ih2lb[(size_t)(nBase + r) * 256 + c8 * 8];
  }
  __syncthreads();
  int lane = tid & 63, w = tid >> 6;
  int lrow = lane & 15, lk = (lane >> 4) * 8;
  f32x4 acc[2];
  acc[0] = (f32x4){0.f, 0.f, 0.f, 0.f};
  acc[1] = (f32x4){0.f, 0.f, 0.f, 0.f};
#pragma unroll
  for (int ks = 0; ks < 8; ++ks) {
    bf16x8 bfr = *(const bf16x8*)&Bs[(w * 16 + lrow) * 264 + ks * 32 + lk];
#pragma unroll
    for (int m = 0; m < 2; ++m) {
      bf16x8 af = *(const bf16x8*)&As[(m * 16 + lrow) * 264 + ks * 32 + lk];
      acc[m] = __builtin_amdgcn_mfma_f32_16x16x32_bf16(af, bfr, acc[m], 0, 0, 0);
    }
  }
  int col = nBase + w * 16 + (lane & 15);
  float bv = bias2[col];
  int orow = (lane >> 4) * 4;
#pragma unroll
  for (int m = 0; m < 2; ++m)
#pragma unroll
    for (int q = 0; q < 4; ++q) {
      int bb = m * 16 + orow + q;
      XW2[((size_t)t * 32 + bb) * G4 + col] = acc[m][q] + bv;
    }
}

// ===========================================================================
// Persistent recurrent kernel. 128 blocks x 256 threads (cooperative).
// Block (b, jq): owns gate rows {g*256 + jq*64 + jj} of BOTH cells.
// All three weight rows live in f16x2 REGISTERS (384 VGPR).
// One h-exchange (h1[T] + h2[T-1]) per step via LLC atomics + flag line.
// ===========================================================================
struct RP {
  const float *X1, *XW2, *bias1, *bias2;
  const u16 *w_hh1h, *w_ih2rh, *w_hh2h;
  float* H1X;   // [110][32][256]
  float* H2X;   // [110][32][256]
  u16* H2NB;    // [29][32][256]
  int* flags;   // [110][32][32] (4 used per line)
};

__global__ __launch_bounds__(256, 1) void recurrent_kernel(RP p) {
  __shared__ float encL[80][264];
  __shared__ __align__(16) f16x2 h1S[128], h2S[128];
  __shared__ float tmp1[256], tmp2[256];
  __shared__ float gsm1[3][64], gsm2[3][64];
  __shared__ float sc[96];
  int bid = blockIdx.x, tid = threadIdx.x;
  int b = bid >> 2, jq = bid & 3;
  int g = tid >> 6, jj = tid & 63;
  int j = (jq << 6) + jj;
  int row = (g << 8) + j;

  f16x2 wA[128], wB[128], wC[128];
  load_wrow16(wA, p.w_hh1h + (size_t)row * 256);
  load_wrow16(wB, p.w_ih2rh + (size_t)row * 256);
  load_wrow16(wC, p.w_hh2h + (size_t)row * 256);
  float c1 = 0.f, c2 = 0.f;
  // per-gate biases for this thread's j (only used by g==0 lanes)
  float b1_0 = p.bias1[j], b1_1 = p.bias1[256 + j], b1_2 = p.bias1[512 + j], b1_3 = p.bias1[768 + j];
  float b2_0 = p.bias2[j], b2_1 = p.bias2[256 + j], b2_2 = p.bias2[512 + j], b2_3 = p.bias2[768 + j];

  for (int T = 0; T < 110; ++T) {
    // prefetch x inputs (independent of exchange)
    float x1_0 = b1_0, x1_1 = b1_1, x1_2 = b1_2, x1_3 = b1_3;
    float x2_0 = b2_0, x2_1 = b2_1, x2_2 = b2_2, x2_3 = b2_3;
    if (g == 0) {
      if (T < TE) {
        const float* xb = &p.X1[((size_t)b * TE + T) * G4 + j];
        x1_0 = xb[0]; x1_1 = xb[256]; x1_2 = xb[512]; x1_3 = xb[768];
      }
      if (T >= 81) {
        const float* xb = &p.XW2[((size_t)(T - 81) * 32 + b) * G4 + j];
        x2_0 = xb[0]; x2_1 = xb[256]; x2_2 = xb[512]; x2_3 = xb[768];
      }
    }
    // ---- exchange: wait flag[T], load h1[T] (+ h2[T-1] for T>=2) ----
    if (T >= 1) {
      if (tid < 4) {
        int gd = 0;
        while (AT_LOAD(&p.flags[((size_t)T * 32 + b) * 32 + tid]) == 0 &&
               ++gd < (1 << 26)) {}
      }
      __syncthreads();
      float h1v = AT_LOAD(&p.H1X[((size_t)T * 32 + b) * 256 + tid]);
      float h2v = (T >= 2) ? AT_LOAD(&p.H2X[((size_t)(T - 1) * 32 + b) * 256 + tid]) : 0.f;
      tmp1[tid] = h1v;
      tmp2[tid] = h2v;
      if (T >= 2 && T <= 81) encL[T - 2][tid] = h2v;  // enc h2 history
      __syncthreads();
      // decoder attention: replace tmp2 (=h2n[s-1]) by ctx
      if (T >= 82) {
        if (tid < TE) {
          const float* e = &encL[tid][0];
          float a = 0.f;
#pragma unroll 8
          for (int k2 = 0; k2 < 256; ++k2) a += e[k2] * tmp2[k2];
          sc[tid] = a;
        }
        __syncthreads();
        if (tid == 0) {
          float m = -INFINITY;
          for (int t2 = 0; t2 < TE; ++t2) m = fmaxf(m, sc[t2]);
          float s = 0.f;
          for (int t2 = 0; t2 < TE; ++t2) { sc[t2] = expf(sc[t2] - m); s += sc[t2]; }
          sc[88] = 1.0f / s;
        }
        __syncthreads();
        float inv = sc[88];
        float a = 0.f;
        for (int t2 = 0; t2 < TE; ++t2) a += sc[t2] * encL[t2][tid];
        __syncthreads();
        tmp2[tid] = a * inv;
        __syncthreads();
      }
      if (tid < 128) {
        h1S[tid] = f16x2{(_Float16)tmp1[2 * tid], (_Float16)tmp1[2 * tid + 1]};
        h2S[tid] = f16x2{(_Float16)tmp2[2 * tid], (_Float16)tmp2[2 * tid + 1]};
      }
      __syncthreads();
    } else {
      if (tid < 128) {
        h1S[tid] = f16x2{(_Float16)0.f, (_Float16)0.f};
        h2S[tid] = f16x2{(_Float16)0.f, (_Float16)0.f};
      }
      __syncthreads();
    }
    // ---- dots ----
    float a1 = 0.f, a2 = 0.f;
    {
      const uint4* h1v4 = (const uint4*)h1S;
      const uint4* h2v4 = (const uint4*)h2S;
#pragma unroll
      for (int q = 0; q < 32; ++q) {
        uint4 u = h1v4[q];
        f16x2 e0 = __builtin_bit_cast(f16x2, u.x), e1 = __builtin_bit_cast(f16x2, u.y);
        f16x2 e2 = __builtin_bit_cast(f16x2, u.z), e3 = __builtin_bit_cast(f16x2, u.w);
        a1 = fdot2h(e0, wA[q * 4 + 0], a1);
        a1 = fdot2h(e1, wA[q * 4 + 1], a1);
        a1 = fdot2h(e2, wA[q * 4 + 2], a1);
        a1 = fdot2h(e3, wA[q * 4 + 3], a1);
        a2 = fdot2h(e0, wB[q * 4 + 0], a2);
        a2 = fdot2h(e1, wB[q * 4 + 1], a2);
        a2 = fdot2h(e2, wB[q * 4 + 2], a2);
        a2 = fdot2h(e3, wB[q * 4 + 3], a2);
      }
#pragma unroll
      for (int q = 0; q < 32; ++q) {
        uint4 u = h2v4[q];
        a2 = fdot2h(__builtin_bit_cast(f16x2, u.x), wC[q * 4 + 0], a2);
        a2 = fdot2h(__builtin_bit_cast(f16x2, u.y), wC[q * 4 + 1], a2);
        a2 = fdot2h(__builtin_bit_cast(f16x2, u.z), wC[q * 4 + 2], a2);
        a2 = fdot2h(__builtin_bit_cast(f16x2, u.w), wC[q * 4 + 3], a2);
      }
    }
    if (g) { gsm1[g - 1][jj] = a1; gsm2[g - 1][jj] = a2; }
    __syncthreads();
    // ---- finalize (g==0 lanes own state for their j) ----
    float h1n = 0.f, h2n_ = 0.f;
    if (g == 0) {
      if (T <= 108) {
        float gi = a1 + x1_0;
        float gf = gsm1[0][jj] + x1_1;
        float gg = gsm1[1][jj] + x1_2;
        float go = gsm1[2][jj] + x1_3;
        c1 = sigm(gf) * c1 + sigm(gi) * tanhf(gg);
        h1n = sigm(go) * tanhf(c1);
      }
      if (T >= 1) {
        float gi = a2 + x2_0;
        float gf = gsm2[0][jj] + x2_1;
        float gg = gsm2[1][jj] + x2_2;
        float go = gsm2[2][jj] + x2_3;
        c2 = sigm(gf) * c2 + sigm(gi) * tanhf(gg);
        h2n_ = sigm(go) * tanhf(c2);
      }
    }
    __syncthreads();
    if (tid < 64) {
      if (T <= 108) AT_STORE(&p.H1X[((size_t)(T + 1) * 32 + b) * 256 + j], h1n);
      if (T >= 1) AT_STORE(&p.H2X[((size_t)T * 32 + b) * 256 + j], h2n_);
      if (T >= 81) p.H2NB[((size_t)(T - 81) * 32 + b) * 256 + j] = f2bf(h2n_);
    }
    asm volatile("s_waitcnt vmcnt(0)" ::: "memory");
    if (tid == 0 && T <= 108)
      AT_STORE(&p.flags[((size_t)(T + 1) * 32 + b) * 32 + jq], 1);
  }
}

// ===========================================================================
// Batched logits + fused CE partials: M=928, N=32000, K=256; A = H2NB bf16.
// ===========================================================================
__global__ __launch_bounds__(256, 1) void logits_ce_kernel(
    const u16* __restrict__ H2NB, const u16* __restrict__ wPK,
    const float* __restrict__ b_out, const int* __restrict__ targets,
    float* __restrict__ pmaxA, float* __restrict__ psumA,
    float* __restrict__ tgtv) {
  __shared__ __align__(16) u16 bS[32768];
  __shared__ __align__(16) u16 aS[32 * 264];
  __shared__ int tS[32];
  int tid = threadIdx.x, bid = blockIdx.x;
  const u16* src = wPK + (size_t)bid * 32768;
  for (int i = tid; i < 4096; i += 256)
    *(uint4*)&bS[i * 8] = *(const uint4*)&src[i * 8];
  int wid = tid >> 6, lane = tid & 63, lcol = lane & 15, lk = lane >> 4;
  float bo[2];
#pragma unroll
  for (int n = 0; n < 2; ++n) bo[n] = b_out[(bid * 8 + wid * 2 + n) * 16 + lcol];

  for (int rg = 0; rg < 29; ++rg) {
    __syncthreads();
    for (int i = tid; i < 1024; i += 256) {
      int r = i >> 5, c8 = i & 31;
      *(uint4*)&aS[r * 264 + c8 * 8] =
          *(const uint4*)&H2NB[(size_t)rg * 8192 + r * 256 + c8 * 8];
    }
    if (tid < 32) tS[tid] = targets[rg * 32 + tid];
    __syncthreads();
    f32x4 acc[2][2];
#pragma unroll
    for (int m = 0; m < 2; ++m)
#pragma unroll
      for (int n = 0; n < 2; ++n) acc[m][n] = (f32x4){0.f, 0.f, 0.f, 0.f};
#pragma unroll
    for (int ks = 0; ks < 8; ++ks) {
      bf16x8 a0 = *(const bf16x8*)&aS[lcol * 264 + ks * 32 + lk * 8];
      bf16x8 a1 = *(const bf16x8*)&aS[(16 + lcol) * 264 + ks * 32 + lk * 8];
      bf16x8 b0 = *(const bf16x8*)&bS[(wid * 2) * 4096 + ((ks * 4 + lk) * 16 + lcol) * 8];
      bf16x8 b1 = *(const bf16x8*)&bS[(wid * 2 + 1) * 4096 + ((ks * 4 + lk) * 16 + lcol) * 8];
      acc[0][0] = __builtin_amdgcn_mfma_f32_16x16x32_bf16(a0, b0, acc[0][0], 0, 0, 0);
      acc[0][1] = __builtin_amdgcn_mfma_f32_16x16x32_bf16(a0, b1, acc[0][1], 0, 0, 0);
      acc[1][0] = __builtin_amdgcn_mfma_f32_16x16x32_bf16(a1, b0, acc[1][0], 0, 0, 0);
      acc[1][1] = __builtin_amdgcn_mfma_f32_16x16x32_bf16(a1, b1, acc[1][1], 0, 0, 0);
    }
    int nbase = (bid * 8 + wid * 2) * 16 + lcol;
#pragma unroll
    for (int m = 0; m < 2; ++m) {
      float pm[4], psv[4];
#pragma unroll
      for (int q = 0; q < 4; ++q) {
        float v0 = acc[m][0][q] + bo[0];
        float v1 = acc[m][1][q] + bo[1];
        int r = m * 16 + lk * 4 + q;
        int tg = tS[r];
        if (tg == nbase) tgtv[rg * 32 + r] = v0;
        if (tg == nbase + 16) tgtv[rg * 32 + r] = v1;
        float mx = fmaxf(v0, v1);
#pragma unroll
        for (int d = 1; d < 16; d <<= 1) mx = fmaxf(mx, __shfl_xor(mx, d));
        float e = expf(v0 - mx) + expf(v1 - mx);
#pragma unroll
        for (int d = 1; d < 16; d <<= 1) e += __shfl_xor(e, d);
        pm[q] = mx;
        psv[q] = e;
      }
      if (lcol == 0) {
        int chunk = bid * 4 + wid;
#pragma unroll
        for (int q = 0; q < 4; ++q) {
          int r2 = rg * 32 + m * 16 + lk * 4 + q;
          pmaxA[(size_t)r2 * 1000 + chunk] = pm[q];
          psumA[(size_t)r2 * 1000 + chunk] = psv[q];
        }
      }
    }
  }
}

__global__ __launch_bounds__(256) void ce_final_kernel(
    const float* __restrict__ pmaxA, const float* __restrict__ psumA,
    const float* __restrict__ tgtv, float* __restrict__ loss) {
  int row = blockIdx.x;
  int tid = threadIdx.x;
  const float* pm = pmaxA + (size_t)row * 1000;
  const float* psv = psumA + (size_t)row * 1000;
  __shared__ float sm[256];
  float m = -INFINITY;
  for (int c = tid; c < 1000; c += 256) m = fmaxf(m, pm[c]);
  sm[tid] = m;
  __syncthreads();
  for (int off = 128; off; off >>= 1) {
    if (tid < off) sm[tid] = fmaxf(sm[tid], sm[tid + off]);
    __syncthreads();
  }
  float M = sm[0];
  __syncthreads();
  float s = 0.f;
  for (int c = tid; c < 1000; c += 256) s += psv[c] * expf(pm[c] - M);
  sm[tid] = s;
  __syncthreads();
  for (int off = 128; off; off >>= 1) {
    if (tid < off) sm[tid] += sm[tid + off];
    __syncthreads();
  }
  if (tid == 0)
    atomicAdd(loss, (M + logf(sm[0]) - tgtv[row]) * (1.0f / 1024.0f));
}

__global__ void finalize_kernel(const float* __restrict__ loss, float* __restrict__ out) {
  if (threadIdx.x == 0) out[0] = loss[0];
}

// ---------------------------------------------------------------------------
extern "C" void kernel_launch(void* const* d_in, const int* in_sizes, int n_in,
                              void* d_out, int out_size, void* d_ws, size_t ws_size,
                              hipStream_t stream) {
  (void)in_sizes; (void)n_in; (void)out_size; (void)ws_size;
  const float* feat    = (const float*)d_in[0];
  const float* caption = (const float*)d_in[1];
  const float* onehot  = (const float*)d_in[2];
  const float* w_ih1   = (const float*)d_in[4];
  const float* w_hh1   = (const float*)d_in[5];
  const float* b_ih1   = (const float*)d_in[6];
  const float* b_hh1   = (const float*)d_in[7];
  const float* w_ih2   = (const float*)d_in[8];
  const float* w_hh2   = (const float*)d_in[9];
  const float* b_ih2   = (const float*)d_in[10];
  const float* b_hh2   = (const float*)d_in[11];
  const float* w_out   = (const float*)d_in[12];
  const float* b_out   = (const float*)d_in[13];

  char* p = (char*)d_ws;
  auto alloc = [&](size_t bytes) {
    char* r = p;
    p += (bytes + 255) & ~(size_t)255;
    return r;
  };
  float* X1      = (float*)alloc(2560ull * 1024 * 4);      // 10.5 MB
  float* XW2     = (float*)alloc(29ull * 32 * 1024 * 4);   // 3.8 MB
  float* bias1   = (float*)alloc(1024 * 4);
  float* bias2   = (float*)alloc(1024 * 4);
  float* H1X     = (float*)alloc(110ull * 8192 * 4);       // 3.6 MB
  float* H2X     = (float*)alloc(110ull * 8192 * 4);       // 3.6 MB
  int*   flags   = (int*)alloc(110ull * 32 * 32 * 4);      // 450 KB
  u16*   H2NB    = (u16*)alloc(29ull * 8192 * 2);
  float* pmaxA   = (float*)alloc(928ull * 1000 * 4);
  float* psumA   = (float*)alloc(928ull * 1000 * 4);
  float* tgtv    = (float*)alloc(928 * 4);
  float* lossacc = (float*)alloc(256);
  int*   targets = (int*)alloc(29 * 32 * 4);
  u16*   w_ih1b  = (u16*)alloc(1024ull * 4096 * 2);        // 8.4 MB
  u16*   w_ih2lb = (u16*)alloc(1024ull * 256 * 2);
  u16*   capb    = (u16*)alloc(32ull * 30 * 256 * 2);
  u16*   w_hh1h  = (u16*)alloc(1024ull * 256 * 2);
  u16*   w_hh2h  = (u16*)alloc(1024ull * 256 * 2);
  u16*   w_ih2rh = (u16*)alloc(1024ull * 256 * 2);
  u16*   wPK     = (u16*)alloc(2000ull * 32 * 16 * 8 * 2); // 16.4 MB

  prep_kernel<<<10729, 256, 0, stream>>>(
      w_ih1, w_out, w_ih2, caption, onehot, w_hh1, w_hh2,
      b_ih1, b_hh1, b_ih2, b_hh2,
      w_ih1b, wPK, w_ih2lb, capb, w_hh1h, w_hh2h, w_ih2rh,
      bias1, bias2, flags, lossacc, targets);
  gemm_x1_kernel<<<dim3(8, 20), 256, 0, stream>>>(feat, w_ih1b, bias1, X1);
  xw2_mfma_kernel<<<dim3(16, 29), 256, 0, stream>>>(capb, w_ih2lb, bias2, XW2);

  RP rp;
  rp.X1 = X1; rp.XW2 = XW2; rp.bias1 = bias1; rp.bias2 = bias2;
  rp.w_hh1h = w_hh1h; rp.w_ih2rh = w_ih2rh; rp.w_hh2h = w_hh2h;
  rp.H1X = H1X; rp.H2X = H2X; rp.H2NB = H2NB; rp.flags = flags;
  void* args[] = {&rp};
  hipLaunchCooperativeKernel((const void*)recurrent_kernel, dim3(128), dim3(256),
                             args, 0, stream);

  logits_ce_kernel<<<250, 256, 0, stream>>>(H2NB, wPK, b_out, targets, pmaxA, psumA, tgtv);
  ce_final_kernel<<<928, 256, 0, stream>>>(pmaxA, psumA, tgtv, lossacc);
  finalize_kernel<<<1, 64, 0, stream>>>(lossacc, (float*)d_out);
}

// Round 8
// 1034.709 us; speedup vs baseline: 2.9645x; 1.4463x over previous
//
#include <hip/hip_runtime.h>
#include <hip/hip_bf16.h>
#include <math.h>

// Problem dims
#define BB 32
#define TE 80
#define FEAT 4096
#define HH 256
#define W2V 256
#define TD 30
#define VV 32000
#define G4 1024   // 4*H

typedef unsigned short u16;
typedef unsigned int u32;
using f32x4 = __attribute__((ext_vector_type(4))) float;
using bf16x8 = __attribute__((ext_vector_type(8))) short;
using f16x2 = __attribute__((ext_vector_type(2))) _Float16;

__device__ __forceinline__ float sigm(float x) { return 1.0f / (1.0f + expf(-x)); }
__device__ __forceinline__ u16 f2bf(float f) {
  u32 u = __float_as_uint(f);
  u32 r = (u + 0x7FFFu + ((u >> 16) & 1u)) >> 16;
  return (u16)r;
}
__device__ __forceinline__ u16 f2h(float f) {
  return __builtin_bit_cast(u16, (_Float16)f);
}
__device__ __forceinline__ u32 packh2(float lo, float hi) {
  f16x2 v = {(_Float16)lo, (_Float16)hi};
  return __builtin_bit_cast(u32, v);
}

#define AT_LOAD(p)     __hip_atomic_load((p), __ATOMIC_RELAXED, __HIP_MEMORY_SCOPE_AGENT)
#define AT_STORE(p, v) __hip_atomic_store((p), (v), __ATOMIC_RELAXED, __HIP_MEMORY_SCOPE_AGENT)

__device__ __forceinline__ float fdot2h(f16x2 a, f16x2 b, float c) {
#if __has_builtin(__builtin_amdgcn_fdot2)
  return __builtin_amdgcn_fdot2(a, b, c, false);
#else
  return c + (float)a[0] * (float)b[0] + (float)a[1] * (float)b[1];
#endif
}

// ===========================================================================
// prep: all one-time elementwise work + argmax, one launch.
// ===========================================================================
__global__ __launch_bounds__(256) void prep_kernel(
    const float* __restrict__ w_ih1, const float* __restrict__ w_out,
    const float* __restrict__ w_ih2, const float* __restrict__ caption,
    const float* __restrict__ onehot,
    const float* __restrict__ w_hh1, const float* __restrict__ w_hh2,
    const float* __restrict__ b_ih1, const float* __restrict__ b_hh1,
    const float* __restrict__ b_ih2, const float* __restrict__ b_hh2,
    u16* __restrict__ w_ih1b, u16* __restrict__ wPK,
    u16* __restrict__ w_ih2lb, u16* __restrict__ capb,
    u16* __restrict__ w_hh1h, u16* __restrict__ w_hh2h, u16* __restrict__ w_ih2rh,
    float* __restrict__ bias1, float* __restrict__ bias2,
    int* __restrict__ flags, float* __restrict__ loss,
    int* __restrict__ targets) {
  int blk = blockIdx.x, tid = threadIdx.x;
  if (blk < 4096) {
    int i = blk * 256 + tid;
    float4 v = *(const float4*)&w_ih1[(size_t)i * 4];
    *(ushort4*)&w_ih1b[(size_t)i * 4] =
        make_ushort4(f2bf(v.x), f2bf(v.y), f2bf(v.z), f2bf(v.w));
  } else if (blk < 8096) {
    int i = (blk - 4096) * 256 + tid;  // (n, kg)
    int n = i >> 5, kg = i & 31;
    float4 v0 = *(const float4*)&w_out[(size_t)n * 256 + kg * 8];
    float4 v1 = *(const float4*)&w_out[(size_t)n * 256 + kg * 8 + 4];
    size_t dst = ((size_t)((n >> 4) * 32 + kg) * 16 + (n & 15)) * 8;
    *(ushort4*)&wPK[dst] = make_ushort4(f2bf(v0.x), f2bf(v0.y), f2bf(v0.z), f2bf(v0.w));
    *(ushort4*)&wPK[dst + 4] = make_ushort4(f2bf(v1.x), f2bf(v1.y), f2bf(v1.z), f2bf(v1.w));
  } else if (blk < 8352) {
    int i = (blk - 8096) * 256 + tid;
    int row = i >> 6, c = i & 63;
    float4 v = *(const float4*)&w_ih2[(size_t)row * 512 + c * 4];
    *(ushort4*)&w_ih2lb[(size_t)row * 256 + c * 4] =
        make_ushort4(f2bf(v.x), f2bf(v.y), f2bf(v.z), f2bf(v.w));
  } else if (blk < 8592) {
    int i = (blk - 8352) * 256 + tid;
    float4 v = *(const float4*)&caption[(size_t)i * 4];
    *(ushort4*)&capb[(size_t)i * 4] =
        make_ushort4(f2bf(v.x), f2bf(v.y), f2bf(v.z), f2bf(v.w));
  } else if (blk < 9033) {
    int i = (blk - 8592) * 256 + tid;
    if (i < 112640) flags[i] = 0;
    if (i < 1024) {
      bias1[i] = b_ih1[i] + b_hh1[i];
      bias2[i] = b_ih2[i] + b_hh2[i];
    }
    if (i == 0) *loss = 0.0f;
  } else if (blk < 9289) {
    int i = (blk - 9033) * 256 + tid;  // w_hh1 -> f16, 65536 float4s
    float4 v = *(const float4*)&w_hh1[(size_t)i * 4];
    *(ushort4*)&w_hh1h[(size_t)i * 4] =
        make_ushort4(f2h(v.x), f2h(v.y), f2h(v.z), f2h(v.w));
  } else if (blk < 9545) {
    int i = (blk - 9289) * 256 + tid;  // w_hh2 -> f16
    float4 v = *(const float4*)&w_hh2[(size_t)i * 4];
    *(ushort4*)&w_hh2h[(size_t)i * 4] =
        make_ushort4(f2h(v.x), f2h(v.y), f2h(v.z), f2h(v.w));
  } else if (blk < 9801) {
    int i = (blk - 9545) * 256 + tid;  // w_ih2[:,256:512] -> f16
    int row = i >> 6, c = i & 63;
    float4 v = *(const float4*)&w_ih2[(size_t)row * 512 + 256 + c * 4];
    *(ushort4*)&w_ih2rh[(size_t)row * 256 + c * 4] =
        make_ushort4(f2h(v.x), f2h(v.y), f2h(v.z), f2h(v.w));
  } else {
    int k = blk - 9801;  // (s-1)*32 + b
    int s = (k >> 5) + 1, b = k & 31;
    const float* row = &onehot[((size_t)b * TD + s) * VV];
    float bv = -INFINITY;
    int bi = 0x7fffffff;
    for (int v = tid; v < VV; v += 256) {
      float x = row[v];
      if (x > bv || (x == bv && v < bi)) { bv = x; bi = v; }
    }
    __shared__ float sv[256];
    __shared__ int si[256];
    sv[tid] = bv; si[tid] = bi;
    __syncthreads();
    for (int off = 128; off; off >>= 1) {
      if (tid < off) {
        float ov = sv[tid + off]; int oi = si[tid + off];
        if (ov > sv[tid] || (ov == sv[tid] && oi < si[tid])) { sv[tid] = ov; si[tid] = oi; }
      }
      __syncthreads();
    }
    if (tid == 0) targets[k] = si[0];
  }
}

// ---------------------------------------------------------------------------
// MFMA GEMM: X1[r][n] = feat[r][:] . w_ih1b[n][:] + bias1[n]   (r = b*80+t)
#define GBM 128
#define GBN 128
#define GBK 64
#define LDSTR 72

__global__ __launch_bounds__(256) void gemm_x1_kernel(
    const float* __restrict__ A, const u16* __restrict__ Bw,
    const float* __restrict__ bias, float* __restrict__ C) {
  __shared__ __align__(16) u16 As[GBM * LDSTR];
  __shared__ __align__(16) u16 Bs[GBN * LDSTR];
  int tid = threadIdx.x;
  int rBase = blockIdx.y * GBM;
  int nBase = blockIdx.x * GBN;
  int lane = tid & 63, w = tid >> 6;
  int wrow = (w >> 1) * 64, wcol = (w & 1) * 64;
  int lrow = lane & 15, lk = (lane >> 4) * 8;

  f32x4 acc[4][4];
#pragma unroll
  for (int m = 0; m < 4; ++m)
#pragma unroll
    for (int n = 0; n < 4; ++n) acc[m][n] = (f32x4){0.f, 0.f, 0.f, 0.f};

  for (int k0 = 0; k0 < FEAT; k0 += GBK) {
#pragma unroll
    for (int i = 0; i < 8; ++i) {
      int f = i * 256 + tid;
      int r = f >> 4, c = (f & 15) << 2;
      float4 v = *(const float4*)&A[(size_t)(rBase + r) * FEAT + k0 + c];
      *(ushort4*)&As[r * LDSTR + c] =
          make_ushort4(f2bf(v.x), f2bf(v.y), f2bf(v.z), f2bf(v.w));
    }
#pragma unroll
    for (int i = 0; i < 4; ++i) {
      int f = i * 256 + tid;
      int r = f >> 3, c = (f & 7) << 3;
      uint4 v = *(const uint4*)&Bw[(size_t)(nBase + r) * FEAT + k0 + c];
      *(uint4*)&Bs[r * LDSTR + c] = v;
    }
    __syncthreads();
    bf16x8 af[4][2], bfr[4][2];
#pragma unroll
    for (int m = 0; m < 4; ++m)
#pragma unroll
      for (int s2 = 0; s2 < 2; ++s2)
        af[m][s2] = *(const bf16x8*)&As[(wrow + m * 16 + lrow) * LDSTR + s2 * 32 + lk];
#pragma unroll
    for (int n = 0; n < 4; ++n)
#pragma unroll
      for (int s2 = 0; s2 < 2; ++s2)
        bfr[n][s2] = *(const bf16x8*)&Bs[(wcol + n * 16 + lrow) * LDSTR + s2 * 32 + lk];
#pragma unroll
    for (int s2 = 0; s2 < 2; ++s2)
#pragma unroll
      for (int m = 0; m < 4; ++m)
#pragma unroll
        for (int n = 0; n < 4; ++n)
          acc[m][n] = __builtin_amdgcn_mfma_f32_16x16x32_bf16(
              af[m][s2], bfr[n][s2], acc[m][n], 0, 0, 0);
    __syncthreads();
  }
  int orow = (lane >> 4) * 4;
  int ocol = lane & 15;
#pragma unroll
  for (int m = 0; m < 4; ++m)
#pragma unroll
    for (int n = 0; n < 4; ++n) {
      int cidx = nBase + wcol + n * 16 + ocol;
      float bv = bias[cidx];
#pragma unroll
      for (int q = 0; q < 4; ++q) {
        int r = rBase + wrow + m * 16 + orow + q;
        C[(size_t)r * G4 + cidx] = acc[m][n][q] + bv;
      }
    }
}

// ---------------------------------------------------------------------------
// MFMA xw2: XW2[(t*32+b)][n] = capb[b][t][:] . w_ih2lb[n][:] + bias2[n]
__global__ __launch_bounds__(256) void xw2_mfma_kernel(
    const u16* __restrict__ capb, const u16* __restrict__ w_ih2lb,
    const float* __restrict__ bias2, float* __restrict__ XW2) {
  __shared__ __align__(16) u16 As[32 * 264];
  __shared__ __align__(16) u16 Bs[64 * 264];
  int tid = threadIdx.x;
  int nBase = blockIdx.x * 64;
  int t = blockIdx.y;
#pragma unroll
  for (int it = 0; it < 4; ++it) {
    int i = it * 256 + tid;
    int r = i >> 5, c8 = i & 31;
    *(uint4*)&As[r * 264 + c8 * 8] =
        *(const uint4*)&capb[((size_t)r * TD + t) * 256 + c8 * 8];
  }
#pragma unroll
  for (int it = 0; it < 8; ++it) {
    int i = it * 256 + tid;
    int r = i >> 5, c8 = i & 31;
    *(uint4*)&Bs[r * 264 + c8 * 8] =
        *(const uint4*)&w_ih2lb[(size_t)(nBase + r) * 256 + c8 * 8];
  }
  __syncthreads();
  int lane = tid & 63, w = tid >> 6;
  int lrow = lane & 15, lk = (lane >> 4) * 8;
  f32x4 acc[2];
  acc[0] = (f32x4){0.f, 0.f, 0.f, 0.f};
  acc[1] = (f32x4){0.f, 0.f, 0.f, 0.f};
#pragma unroll
  for (int ks = 0; ks < 8; ++ks) {
    bf16x8 bfr = *(const bf16x8*)&Bs[(w * 16 + lrow) * 264 + ks * 32 + lk];
#pragma unroll
    for (int m = 0; m < 2; ++m) {
      bf16x8 af = *(const bf16x8*)&As[(m * 16 + lrow) * 264 + ks * 32 + lk];
      acc[m] = __builtin_amdgcn_mfma_f32_16x16x32_bf16(af, bfr, acc[m], 0, 0, 0);
    }
  }
  int col = nBase + w * 16 + (lane & 15);
  float bv = bias2[col];
  int orow = (lane >> 4) * 4;
#pragma unroll
  for (int m = 0; m < 2; ++m)
#pragma unroll
    for (int q = 0; q < 4; ++q) {
      int bb = m * 16 + orow + q;
      XW2[((size_t)t * 32 + bb) * G4 + col] = acc[m][q] + bv;
    }
}

// ===========================================================================
// Persistent recurrent kernel. 256 blocks x 256 threads (cooperative).
// Block (b, oct): owns j in [oct*32, oct*32+32) for all 4 gates of BOTH cells.
// Per thread: half-rows of 3 matrices = 192 f16x2 VGPRs (fits under the 256
// architectural VALU cap -> no scratch spill).
// One packed-f16 h-exchange (h1[T] + h2[T-1]) per step via LLC atomics+flags.
// ===========================================================================
struct RP {
  const float *X1, *XW2, *bias1, *bias2;
  const u16 *w_hh1h, *w_ih2rh, *w_hh2h;
  u32* H1H;     // [110][32][128] packed f16x2 of h1[T]
  u32* H2H;     // [110][32][128] packed f16x2 of h2[T]
  u16* H2NB;    // [29][32][256] bf16 decoder h2n
  int* flags;   // [110][32][32]
};

__global__ __launch_bounds__(256, 1) void recurrent_kernel(RP p) {
  __shared__ float encL[TE][257];             // 82 KB, stride 257 (conflict-free)
  __shared__ __align__(16) f16x2 h1S[128], h2S[128];
  __shared__ float tmp2[256];
  __shared__ float gb[2][128];
  __shared__ float hnew1[32], hnew2[32];
  __shared__ float cS1[32], cS2[32];
  __shared__ float sc[96];
  int bid = blockIdx.x, tid = threadIdx.x;
  int b = bid >> 3, oct = bid & 7;
  int r = tid >> 1, half = tid & 1;           // row in [0,128), k-half
  int gg_ = r >> 5, uu_ = r & 31;
  int grow = (gg_ << 8) + (oct << 5) + uu_;   // global gate row

  // weights: thread's k-half of its row in each of 3 matrices (192 VGPRs)
  f16x2 wA[64], wB[64], wC[64];
  {
    const uint4* a4 = (const uint4*)(p.w_hh1h + (size_t)grow * 256 + half * 128);
    const uint4* b4 = (const uint4*)(p.w_ih2rh + (size_t)grow * 256 + half * 128);
    const uint4* c4 = (const uint4*)(p.w_hh2h + (size_t)grow * 256 + half * 128);
#pragma unroll
    for (int q = 0; q < 16; ++q) {
      uint4 ua = a4[q];
      wA[q * 4 + 0] = __builtin_bit_cast(f16x2, ua.x);
      wA[q * 4 + 1] = __builtin_bit_cast(f16x2, ua.y);
      wA[q * 4 + 2] = __builtin_bit_cast(f16x2, ua.z);
      wA[q * 4 + 3] = __builtin_bit_cast(f16x2, ua.w);
      uint4 ub = b4[q];
      wB[q * 4 + 0] = __builtin_bit_cast(f16x2, ub.x);
      wB[q * 4 + 1] = __builtin_bit_cast(f16x2, ub.y);
      wB[q * 4 + 2] = __builtin_bit_cast(f16x2, ub.z);
      wB[q * 4 + 3] = __builtin_bit_cast(f16x2, ub.w);
      uint4 uc = c4[q];
      wC[q * 4 + 0] = __builtin_bit_cast(f16x2, uc.x);
      wC[q * 4 + 1] = __builtin_bit_cast(f16x2, uc.y);
      wC[q * 4 + 2] = __builtin_bit_cast(f16x2, uc.z);
      wC[q * 4 + 3] = __builtin_bit_cast(f16x2, uc.w);
    }
  }
  float b1v[4], b2v[4];
  if (tid < 32) {
    int j = (oct << 5) + tid;
#pragma unroll
    for (int g2 = 0; g2 < 4; ++g2) {
      b1v[g2] = p.bias1[g2 * 256 + j];
      b2v[g2] = p.bias2[g2 * 256 + j];
    }
    cS1[tid] = 0.f;
    cS2[tid] = 0.f;
  }
  if (tid < 128) {
    h1S[tid] = f16x2{(_Float16)0.f, (_Float16)0.f};
    h2S[tid] = f16x2{(_Float16)0.f, (_Float16)0.f};
  }
  __syncthreads();

  for (int T = 0; T < 110; ++T) {
    // ---- x prefetch (plain loads, overlap with exchange wait) ----
    float x1v[4], x2v[4];
    if (tid < 32) {
      int j = (oct << 5) + tid;
#pragma unroll
      for (int g2 = 0; g2 < 4; ++g2) { x1v[g2] = b1v[g2]; x2v[g2] = b2v[g2]; }
      if (T < TE) {
        const float* xb = &p.X1[((size_t)b * TE + T) * G4 + j];
#pragma unroll
        for (int g2 = 0; g2 < 4; ++g2) x1v[g2] = xb[g2 * 256];
      }
      if (T >= 81) {
        const float* xb = &p.XW2[((size_t)(T - 81) * 32 + b) * G4 + j];
#pragma unroll
        for (int g2 = 0; g2 < 4; ++g2) x2v[g2] = xb[g2 * 256];
      }
    }
    // ---- exchange: wait 8 flags, load h1[T] (+ h2[T-1]) packed f16 ----
    if (T >= 1) {
      if (tid < 8) {
        int gd = 0;
        while (AT_LOAD(&p.flags[((size_t)T * 32 + b) * 32 + tid]) == 0 &&
               ++gd < (1 << 26)) {}
      }
      __syncthreads();
      if (tid < 128) {
        u32 v = AT_LOAD(&p.H1H[((size_t)T * 32 + b) * 128 + tid]);
        h1S[tid] = __builtin_bit_cast(f16x2, v);
      } else {
        int t2 = tid - 128;
        u32 v = 0;
        if (T >= 2) v = AT_LOAD(&p.H2H[((size_t)(T - 1) * 32 + b) * 128 + t2]);
        f16x2 hp = __builtin_bit_cast(f16x2, v);
        h2S[t2] = hp;
        tmp2[2 * t2] = (float)hp[0];
        tmp2[2 * t2 + 1] = (float)hp[1];
      }
      __syncthreads();
      if (T >= 2 && T <= 81) encL[T - 2][tid] = tmp2[tid];
      if (T >= 82) {
        // attention: q = tmp2 (h2n[s-1]); ctx replaces h2 input
        if (tid < TE) {
          const float* e = &encL[tid][0];
          float a = 0.f;
#pragma unroll 8
          for (int k2 = 0; k2 < 256; ++k2) a += e[k2] * tmp2[k2];
          sc[tid] = a;
        }
        __syncthreads();
        if (tid == 0) {
          float m = -INFINITY;
          for (int t2 = 0; t2 < TE; ++t2) m = fmaxf(m, sc[t2]);
          float s = 0.f;
          for (int t2 = 0; t2 < TE; ++t2) { sc[t2] = expf(sc[t2] - m); s += sc[t2]; }
          sc[88] = 1.0f / s;
        }
        __syncthreads();
        float inv = sc[88];
        float a = 0.f;
        for (int t2 = 0; t2 < TE; ++t2) a += sc[t2] * encL[t2][tid];
        tmp2[tid] = a * inv;
        __syncthreads();
        if (tid < 128)
          h2S[tid] = f16x2{(_Float16)tmp2[2 * tid], (_Float16)tmp2[2 * tid + 1]};
        __syncthreads();
      }
    }
    // ---- dots: a1 = wA.h1 (lstm1), a2 = wB.h1 + wC.h2 (lstm2) ----
    float a1 = 0.f, a2 = 0.f;
    {
      const uint4* h1v = ((const uint4*)h1S) + half * 16;
      const uint4* h2v = ((const uint4*)h2S) + half * 16;
#pragma unroll
      for (int q = 0; q < 16; ++q) {
        uint4 uu = h1v[q];
        f16x2 e0 = __builtin_bit_cast(f16x2, uu.x), e1 = __builtin_bit_cast(f16x2, uu.y);
        f16x2 e2 = __builtin_bit_cast(f16x2, uu.z), e3 = __builtin_bit_cast(f16x2, uu.w);
        a1 = fdot2h(e0, wA[q * 4 + 0], a1);
        a1 = fdot2h(e1, wA[q * 4 + 1], a1);
        a1 = fdot2h(e2, wA[q * 4 + 2], a1);
        a1 = fdot2h(e3, wA[q * 4 + 3], a1);
        a2 = fdot2h(e0, wB[q * 4 + 0], a2);
        a2 = fdot2h(e1, wB[q * 4 + 1], a2);
        a2 = fdot2h(e2, wB[q * 4 + 2], a2);
        a2 = fdot2h(e3, wB[q * 4 + 3], a2);
      }
#pragma unroll
      for (int q = 0; q < 16; ++q) {
        uint4 uu = h2v[q];
        a2 = fdot2h(__builtin_bit_cast(f16x2, uu.x), wC[q * 4 + 0], a2);
        a2 = fdot2h(__builtin_bit_cast(f16x2, uu.y), wC[q * 4 + 1], a2);
        a2 = fdot2h(__builtin_bit_cast(f16x2, uu.z), wC[q * 4 + 2], a2);
        a2 = fdot2h(__builtin_bit_cast(f16x2, uu.w), wC[q * 4 + 3], a2);
      }
    }
    a1 += __shfl_xor(a1, 1);
    a2 += __shfl_xor(a2, 1);
    if (half == 0) { gb[0][r] = a1; gb[1][r] = a2; }
    __syncthreads();
    // ---- finalize states (tid<32, u = tid) ----
    if (tid < 32) {
      int u = tid;
      if (T <= 108) {
        float gi = gb[0][u] + x1v[0];
        float gf = gb[0][32 + u] + x1v[1];
        float gG = gb[0][64 + u] + x1v[2];
        float go = gb[0][96 + u] + x1v[3];
        float c = sigm(gf) * cS1[u] + sigm(gi) * tanhf(gG);
        cS1[u] = c;
        hnew1[u] = sigm(go) * tanhf(c);
      }
      if (T >= 1) {
        float gi = gb[1][u] + x2v[0];
        float gf = gb[1][32 + u] + x2v[1];
        float gG = gb[1][64 + u] + x2v[2];
        float go = gb[1][96 + u] + x2v[3];
        float c = sigm(gf) * cS2[u] + sigm(gi) * tanhf(gG);
        float h = sigm(go) * tanhf(c);
        cS2[u] = c;
        hnew2[u] = h;
        if (T >= 81)
          p.H2NB[((size_t)(T - 81) * 32 + b) * 256 + (oct << 5) + u] = f2bf(h);
      }
    }
    // ---- pack + publish (all publishing lanes in wave 0) ----
    if (tid < 16) {
      if (T <= 108) {
        u32 pk = packh2(hnew1[2 * tid], hnew1[2 * tid + 1]);
        AT_STORE(&p.H1H[((size_t)(T + 1) * 32 + b) * 128 + (oct << 4) + tid], pk);
      }
    } else if (tid < 32) {
      if (T >= 1) {
        int t2 = tid - 16;
        u32 pk = packh2(hnew2[2 * t2], hnew2[2 * t2 + 1]);
        AT_STORE(&p.H2H[((size_t)T * 32 + b) * 128 + (oct << 4) + t2], pk);
      }
    }
    asm volatile("s_waitcnt vmcnt(0)" ::: "memory");
    if (tid == 0 && T <= 108)
      AT_STORE(&p.flags[((size_t)(T + 1) * 32 + b) * 32 + oct], 1);
  }
}

// ===========================================================================
// Batched logits + fused CE partials: M=928, N=32000, K=256; A = H2NB bf16.
// ===========================================================================
__global__ __launch_bounds__(256, 1) void logits_ce_kernel(
    const u16* __restrict__ H2NB, const u16* __restrict__ wPK,
    const float* __restrict__ b_out, const int* __restrict__ targets,
    float* __restrict__ pmaxA, float* __restrict__ psumA,
    float* __restrict__ tgtv) {
  __shared__ __align__(16) u16 bS[32768];
  __shared__ __align__(16) u16 aS[32 * 264];
  __shared__ int tS[32];
  int tid = threadIdx.x, bid = blockIdx.x;
  const u16* src = wPK + (size_t)bid * 32768;
  for (int i = tid; i < 4096; i += 256)
    *(uint4*)&bS[i * 8] = *(const uint4*)&src[i * 8];
  int wid = tid >> 6, lane = tid & 63, lcol = lane & 15, lk = lane >> 4;
  float bo[2];
#pragma unroll
  for (int n = 0; n < 2; ++n) bo[n] = b_out[(bid * 8 + wid * 2 + n) * 16 + lcol];

  for (int rg = 0; rg < 29; ++rg) {
    __syncthreads();
    for (int i = tid; i < 1024; i += 256) {
      int r = i >> 5, c8 = i & 31;
      *(uint4*)&aS[r * 264 + c8 * 8] =
          *(const uint4*)&H2NB[(size_t)rg * 8192 + r * 256 + c8 * 8];
    }
    if (tid < 32) tS[tid] = targets[rg * 32 + tid];
    __syncthreads();
    f32x4 acc[2][2];
#pragma unroll
    for (int m = 0; m < 2; ++m)
#pragma unroll
      for (int n = 0; n < 2; ++n) acc[m][n] = (f32x4){0.f, 0.f, 0.f, 0.f};
#pragma unroll
    for (int ks = 0; ks < 8; ++ks) {
      bf16x8 a0 = *(const bf16x8*)&aS[lcol * 264 + ks * 32 + lk * 8];
      bf16x8 a1 = *(const bf16x8*)&aS[(16 + lcol) * 264 + ks * 32 + lk * 8];
      bf16x8 b0 = *(const bf16x8*)&bS[(wid * 2) * 4096 + ((ks * 4 + lk) * 16 + lcol) * 8];
      bf16x8 b1 = *(const bf16x8*)&bS[(wid * 2 + 1) * 4096 + ((ks * 4 + lk) * 16 + lcol) * 8];
      acc[0][0] = __builtin_amdgcn_mfma_f32_16x16x32_bf16(a0, b0, acc[0][0], 0, 0, 0);
      acc[0][1] = __builtin_amdgcn_mfma_f32_16x16x32_bf16(a0, b1, acc[0][1], 0, 0, 0);
      acc[1][0] = __builtin_amdgcn_mfma_f32_16x16x32_bf16(a1, b0, acc[1][0], 0, 0, 0);
      acc[1][1] = __builtin_amdgcn_mfma_f32_16x16x32_bf16(a1, b1, acc[1][1], 0, 0, 0);
    }
    int nbase = (bid * 8 + wid * 2) * 16 + lcol;
#pragma unroll
    for (int m = 0; m < 2; ++m) {
      float pm[4], psv[4];
#pragma unroll
      for (int q = 0; q < 4; ++q) {
        float v0 = acc[m][0][q] + bo[0];
        float v1 = acc[m][1][q] + bo[1];
        int r = m * 16 + lk * 4 + q;
        int tg = tS[r];
        if (tg == nbase) tgtv[rg * 32 + r] = v0;
        if (tg == nbase + 16) tgtv[rg * 32 + r] = v1;
        float mx = fmaxf(v0, v1);
#pragma unroll
        for (int d = 1; d < 16; d <<= 1) mx = fmaxf(mx, __shfl_xor(mx, d));
        float e = expf(v0 - mx) + expf(v1 - mx);
#pragma unroll
        for (int d = 1; d < 16; d <<= 1) e += __shfl_xor(e, d);
        pm[q] = mx;
        psv[q] = e;
      }
      if (lcol == 0) {
        int chunk = bid * 4 + wid;
#pragma unroll
        for (int q = 0; q < 4; ++q) {
          int r2 = rg * 32 + m * 16 + lk * 4 + q;
          pmaxA[(size_t)r2 * 1000 + chunk] = pm[q];
          psumA[(size_t)r2 * 1000 + chunk] = psv[q];
        }
      }
    }
  }
}

__global__ __launch_bounds__(256) void ce_final_kernel(
    const float* __restrict__ pmaxA, const float* __restrict__ psumA,
    const float* __restrict__ tgtv, float* __restrict__ loss) {
  int row = blockIdx.x;
  int tid = threadIdx.x;
  const float* pm = pmaxA + (size_t)row * 1000;
  const float* psv = psumA + (size_t)row * 1000;
  __shared__ float sm[256];
  float m = -INFINITY;
  for (int c = tid; c < 1000; c += 256) m = fmaxf(m, pm[c]);
  sm[tid] = m;
  __syncthreads();
  for (int off = 128; off; off >>= 1) {
    if (tid < off) sm[tid] = fmaxf(sm[tid], sm[tid + off]);
    __syncthreads();
  }
  float M = sm[0];
  __syncthreads();
  float s = 0.f;
  for (int c = tid; c < 1000; c += 256) s += psv[c] * expf(pm[c] - M);
  sm[tid] = s;
  __syncthreads();
  for (int off = 128; off; off >>= 1) {
    if (tid < off) sm[tid] += sm[tid + off];
    __syncthreads();
  }
  if (tid == 0)
    atomicAdd(loss, (M + logf(sm[0]) - tgtv[row]) * (1.0f / 1024.0f));
}

__global__ void finalize_kernel(const float* __restrict__ loss, float* __restrict__ out) {
  if (threadIdx.x == 0) out[0] = loss[0];
}

// ---------------------------------------------------------------------------
extern "C" void kernel_launch(void* const* d_in, const int* in_sizes, int n_in,
                              void* d_out, int out_size, void* d_ws, size_t ws_size,
                              hipStream_t stream) {
  (void)in_sizes; (void)n_in; (void)out_size; (void)ws_size;
  const float* feat    = (const float*)d_in[0];
  const float* caption = (const float*)d_in[1];
  const float* onehot  = (const float*)d_in[2];
  const float* w_ih1   = (const float*)d_in[4];
  const float* w_hh1   = (const float*)d_in[5];
  const float* b_ih1   = (const float*)d_in[6];
  const float* b_hh1   = (const float*)d_in[7];
  const float* w_ih2   = (const float*)d_in[8];
  const float* w_hh2   = (const float*)d_in[9];
  const float* b_ih2   = (const float*)d_in[10];
  const float* b_hh2   = (const float*)d_in[11];
  const float* w_out   = (const float*)d_in[12];
  const float* b_out   = (const float*)d_in[13];

  char* p = (char*)d_ws;
  auto alloc = [&](size_t bytes) {
    char* r = p;
    p += (bytes + 255) & ~(size_t)255;
    return r;
  };
  float* X1      = (float*)alloc(2560ull * 1024 * 4);      // 10.5 MB
  float* XW2     = (float*)alloc(29ull * 32 * 1024 * 4);   // 3.8 MB
  float* bias1   = (float*)alloc(1024 * 4);
  float* bias2   = (float*)alloc(1024 * 4);
  u32*   H1H     = (u32*)alloc(110ull * 32 * 128 * 4);     // 1.8 MB
  u32*   H2H     = (u32*)alloc(110ull * 32 * 128 * 4);     // 1.8 MB
  int*   flags   = (int*)alloc(110ull * 32 * 32 * 4);      // 450 KB
  u16*   H2NB    = (u16*)alloc(29ull * 8192 * 2);
  float* pmaxA   = (float*)alloc(928ull * 1000 * 4);
  float* psumA   = (float*)alloc(928ull * 1000 * 4);
  float* tgtv    = (float*)alloc(928 * 4);
  float* lossacc = (float*)alloc(256);
  int*   targets = (int*)alloc(29 * 32 * 4);
  u16*   w_ih1b  = (u16*)alloc(1024ull * 4096 * 2);        // 8.4 MB
  u16*   w_ih2lb = (u16*)alloc(1024ull * 256 * 2);
  u16*   capb    = (u16*)alloc(32ull * 30 * 256 * 2);
  u16*   w_hh1h  = (u16*)alloc(1024ull * 256 * 2);
  u16*   w_hh2h  = (u16*)alloc(1024ull * 256 * 2);
  u16*   w_ih2rh = (u16*)alloc(1024ull * 256 * 2);
  u16*   wPK     = (u16*)alloc(2000ull * 32 * 16 * 8 * 2); // 16.4 MB

  prep_kernel<<<10729, 256, 0, stream>>>(
      w_ih1, w_out, w_ih2, caption, onehot, w_hh1, w_hh2,
      b_ih1, b_hh1, b_ih2, b_hh2,
      w_ih1b, wPK, w_ih2lb, capb, w_hh1h, w_hh2h, w_ih2rh,
      bias1, bias2, flags, lossacc, targets);
  gemm_x1_kernel<<<dim3(8, 20), 256, 0, stream>>>(feat, w_ih1b, bias1, X1);
  xw2_mfma_kernel<<<dim3(16, 29), 256, 0, stream>>>(capb, w_ih2lb, bias2, XW2);

  RP rp;
  rp.X1 = X1; rp.XW2 = XW2; rp.bias1 = bias1; rp.bias2 = bias2;
  rp.w_hh1h = w_hh1h; rp.w_ih2rh = w_ih2rh; rp.w_hh2h = w_hh2h;
  rp.H1H = H1H; rp.H2H = H2H; rp.H2NB = H2NB; rp.flags = flags;
  void* args[] = {&rp};
  hipLaunchCooperativeKernel((const void*)recurrent_kernel, dim3(256), dim3(256),
                             args, 0, stream);

  logits_ce_kernel<<<250, 256, 0, stream>>>(H2NB, wPK, b_out, targets, pmaxA, psumA, tgtv);
  ce_final_kernel<<<928, 256, 0, stream>>>(pmaxA, psumA, tgtv, lossacc);
  finalize_kernel<<<1, 64, 0, stream>>>(lossacc, (float*)d_out);
}

// Round 9
// 930.923 us; speedup vs baseline: 3.2950x; 1.1115x over previous
//
#include <hip/hip_runtime.h>
#include <hip/hip_bf16.h>
#include <math.h>

// Problem dims
#define BB 32
#define TE 80
#define FEAT 4096
#define HH 256
#define W2V 256
#define TD 30
#define VV 32000
#define G4 1024   // 4*H

typedef unsigned short u16;
typedef unsigned int u32;
using f32x4 = __attribute__((ext_vector_type(4))) float;
using bf16x8 = __attribute__((ext_vector_type(8))) short;
using f16x2 = __attribute__((ext_vector_type(2))) _Float16;

#define SENT 0xFFFFFFFFu

__device__ __forceinline__ float sigm(float x) { return 1.0f / (1.0f + expf(-x)); }
__device__ __forceinline__ u16 f2bf(float f) {
  u32 u = __float_as_uint(f);
  u32 r = (u + 0x7FFFu + ((u >> 16) & 1u)) >> 16;
  return (u16)r;
}
__device__ __forceinline__ u16 f2h(float f) {
  return __builtin_bit_cast(u16, (_Float16)f);
}
__device__ __forceinline__ u32 packh2(float lo, float hi) {
  f16x2 v = {(_Float16)lo, (_Float16)hi};
  return __builtin_bit_cast(u32, v);
}

#define AT_LOAD(p)     __hip_atomic_load((p), __ATOMIC_RELAXED, __HIP_MEMORY_SCOPE_AGENT)
#define AT_STORE(p, v) __hip_atomic_store((p), (v), __ATOMIC_RELAXED, __HIP_MEMORY_SCOPE_AGENT)

__device__ __forceinline__ float fdot2h(f16x2 a, f16x2 b, float c) {
#if __has_builtin(__builtin_amdgcn_fdot2)
  return __builtin_amdgcn_fdot2(a, b, c, false);
#else
  return c + (float)a[0] * (float)b[0] + (float)a[1] * (float)b[1];
#endif
}

// ===========================================================================
// prep: all one-time elementwise work + sentinel init + argmax, one launch.
// ===========================================================================
__global__ __launch_bounds__(256) void prep_kernel(
    const float* __restrict__ w_ih1, const float* __restrict__ w_out,
    const float* __restrict__ w_ih2, const float* __restrict__ caption,
    const float* __restrict__ onehot,
    const float* __restrict__ w_hh1, const float* __restrict__ w_hh2,
    const float* __restrict__ b_ih1, const float* __restrict__ b_hh1,
    const float* __restrict__ b_ih2, const float* __restrict__ b_hh2,
    u16* __restrict__ w_ih1b, u16* __restrict__ wPK,
    u16* __restrict__ w_ih2lb, u16* __restrict__ capb,
    u16* __restrict__ w_hh1h, u16* __restrict__ w_hh2h, u16* __restrict__ w_ih2rh,
    float* __restrict__ bias1, float* __restrict__ bias2,
    u32* __restrict__ H1H, u32* __restrict__ H2H,
    float* __restrict__ loss, int* __restrict__ cectr,
    int* __restrict__ targets) {
  int blk = blockIdx.x, tid = threadIdx.x;
  if (blk < 4096) {
    int i = blk * 256 + tid;
    float4 v = *(const float4*)&w_ih1[(size_t)i * 4];
    *(ushort4*)&w_ih1b[(size_t)i * 4] =
        make_ushort4(f2bf(v.x), f2bf(v.y), f2bf(v.z), f2bf(v.w));
  } else if (blk < 8096) {
    int i = (blk - 4096) * 256 + tid;  // (n, kg)
    int n = i >> 5, kg = i & 31;
    float4 v0 = *(const float4*)&w_out[(size_t)n * 256 + kg * 8];
    float4 v1 = *(const float4*)&w_out[(size_t)n * 256 + kg * 8 + 4];
    size_t dst = ((size_t)((n >> 4) * 32 + kg) * 16 + (n & 15)) * 8;
    *(ushort4*)&wPK[dst] = make_ushort4(f2bf(v0.x), f2bf(v0.y), f2bf(v0.z), f2bf(v0.w));
    *(ushort4*)&wPK[dst + 4] = make_ushort4(f2bf(v1.x), f2bf(v1.y), f2bf(v1.z), f2bf(v1.w));
  } else if (blk < 8352) {
    int i = (blk - 8096) * 256 + tid;
    int row = i >> 6, c = i & 63;
    float4 v = *(const float4*)&w_ih2[(size_t)row * 512 + c * 4];
    *(ushort4*)&w_ih2lb[(size_t)row * 256 + c * 4] =
        make_ushort4(f2bf(v.x), f2bf(v.y), f2bf(v.z), f2bf(v.w));
  } else if (blk < 8592) {
    int i = (blk - 8352) * 256 + tid;
    float4 v = *(const float4*)&caption[(size_t)i * 4];
    *(ushort4*)&capb[(size_t)i * 4] =
        make_ushort4(f2bf(v.x), f2bf(v.y), f2bf(v.z), f2bf(v.w));
  } else if (blk < 9032) {
    int i = (blk - 8592) * 256 + tid;  // < 112640
    u32 v = (i < 4096) ? 0u : SENT;    // slot T=0 = packed zeros, rest sentinel
    H1H[i] = v;
    H2H[i] = v;
    if (i < 1024) {
      bias1[i] = b_ih1[i] + b_hh1[i];
      bias2[i] = b_ih2[i] + b_hh2[i];
    }
    if (i == 0) { *loss = 0.0f; *cectr = 0; }
  } else if (blk < 9288) {
    int i = (blk - 9032) * 256 + tid;  // w_hh1 -> f16, 65536 float4s
    float4 v = *(const float4*)&w_hh1[(size_t)i * 4];
    *(ushort4*)&w_hh1h[(size_t)i * 4] =
        make_ushort4(f2h(v.x), f2h(v.y), f2h(v.z), f2h(v.w));
  } else if (blk < 9544) {
    int i = (blk - 9288) * 256 + tid;  // w_hh2 -> f16
    float4 v = *(const float4*)&w_hh2[(size_t)i * 4];
    *(ushort4*)&w_hh2h[(size_t)i * 4] =
        make_ushort4(f2h(v.x), f2h(v.y), f2h(v.z), f2h(v.w));
  } else if (blk < 9800) {
    int i = (blk - 9544) * 256 + tid;  // w_ih2[:,256:512] -> f16
    int row = i >> 6, c = i & 63;
    float4 v = *(const float4*)&w_ih2[(size_t)row * 512 + 256 + c * 4];
    *(ushort4*)&w_ih2rh[(size_t)row * 256 + c * 4] =
        make_ushort4(f2h(v.x), f2h(v.y), f2h(v.z), f2h(v.w));
  } else {
    int k = blk - 9800;  // (s-1)*32 + b
    int s = (k >> 5) + 1, b = k & 31;
    const float* row = &onehot[((size_t)b * TD + s) * VV];
    float bv = -INFINITY;
    int bi = 0x7fffffff;
    for (int v = tid; v < VV; v += 256) {
      float x = row[v];
      if (x > bv || (x == bv && v < bi)) { bv = x; bi = v; }
    }
    __shared__ float sv[256];
    __shared__ int si[256];
    sv[tid] = bv; si[tid] = bi;
    __syncthreads();
    for (int off = 128; off; off >>= 1) {
      if (tid < off) {
        float ov = sv[tid + off]; int oi = si[tid + off];
        if (ov > sv[tid] || (ov == sv[tid] && oi < si[tid])) { sv[tid] = ov; si[tid] = oi; }
      }
      __syncthreads();
    }
    if (tid == 0) targets[k] = si[0];
  }
}

// ===========================================================================
// Fused one-time GEMMs: blocks [0,160) = X1 MFMA GEMM; [160,624) = XW2.
// ===========================================================================
#define GBM 128
#define GBN 128
#define GBK 64
#define LDSTR 72

__device__ void gemm_x1_body(char* smem, int bx, int by,
                             const float* __restrict__ A, const u16* __restrict__ Bw,
                             const float* __restrict__ bias, float* __restrict__ C) {
  u16* As = (u16*)smem;                 // 128*72*2 = 18432
  u16* Bs = (u16*)(smem + 18432);       // 18432
  int tid = threadIdx.x;
  int rBase = by * GBM;
  int nBase = bx * GBN;
  int lane = tid & 63, w = tid >> 6;
  int wrow = (w >> 1) * 64, wcol = (w & 1) * 64;
  int lrow = lane & 15, lk = (lane >> 4) * 8;

  f32x4 acc[4][4];
#pragma unroll
  for (int m = 0; m < 4; ++m)
#pragma unroll
    for (int n = 0; n < 4; ++n) acc[m][n] = (f32x4){0.f, 0.f, 0.f, 0.f};

  for (int k0 = 0; k0 < FEAT; k0 += GBK) {
#pragma unroll
    for (int i = 0; i < 8; ++i) {
      int f = i * 256 + tid;
      int r = f >> 4, c = (f & 15) << 2;
      float4 v = *(const float4*)&A[(size_t)(rBase + r) * FEAT + k0 + c];
      *(ushort4*)&As[r * LDSTR + c] =
          make_ushort4(f2bf(v.x), f2bf(v.y), f2bf(v.z), f2bf(v.w));
    }
#pragma unroll
    for (int i = 0; i < 4; ++i) {
      int f = i * 256 + tid;
      int r = f >> 3, c = (f & 7) << 3;
      uint4 v = *(const uint4*)&Bw[(size_t)(nBase + r) * FEAT + k0 + c];
      *(uint4*)&Bs[r * LDSTR + c] = v;
    }
    __syncthreads();
#pragma unroll
    for (int s2 = 0; s2 < 2; ++s2) {
      bf16x8 af[4], bfr[4];
#pragma unroll
      for (int m = 0; m < 4; ++m)
        af[m] = *(const bf16x8*)&As[(wrow + m * 16 + lrow) * LDSTR + s2 * 32 + lk];
#pragma unroll
      for (int n = 0; n < 4; ++n)
        bfr[n] = *(const bf16x8*)&Bs[(wcol + n * 16 + lrow) * LDSTR + s2 * 32 + lk];
#pragma unroll
      for (int m = 0; m < 4; ++m)
#pragma unroll
        for (int n = 0; n < 4; ++n)
          acc[m][n] = __builtin_amdgcn_mfma_f32_16x16x32_bf16(
              af[m], bfr[n], acc[m][n], 0, 0, 0);
    }
    __syncthreads();
  }
  int orow = (lane >> 4) * 4;
  int ocol = lane & 15;
#pragma unroll
  for (int m = 0; m < 4; ++m)
#pragma unroll
    for (int n = 0; n < 4; ++n) {
      int cidx = nBase + wcol + n * 16 + ocol;
      float bv = bias[cidx];
#pragma unroll
      for (int q = 0; q < 4; ++q) {
        int r = rBase + wrow + m * 16 + orow + q;
        C[(size_t)r * G4 + cidx] = acc[m][n][q] + bv;
      }
    }
}

__device__ void xw2_body(char* smem, int nb, int t,
                         const u16* __restrict__ capb, const u16* __restrict__ w_ih2lb,
                         const float* __restrict__ bias2, float* __restrict__ XW2) {
  u16* As = (u16*)smem;                 // 32*264*2 = 16896
  u16* Bs = (u16*)(smem + 16896);       // 64*264*2 = 33792
  int tid = threadIdx.x;
  int nBase = nb * 64;
#pragma unroll
  for (int it = 0; it < 4; ++it) {
    int i = it * 256 + tid;
    int r = i >> 5, c8 = i & 31;
    *(uint4*)&As[r * 264 + c8 * 8] =
        *(const uint4*)&capb[((size_t)r * TD + t) * 256 + c8 * 8];
  }
#pragma unroll
  for (int it = 0; it < 8; ++it) {
    int i = it * 256 + tid;
    int r = i >> 5, c8 = i & 31;
    *(uint4*)&Bs[r * 264 + c8 * 8] =
        *(const uint4*)&w_ih2lb[(size_t)(nBase + r) * 256 + c8 * 8];
  }
  __syncthreads();
  int lane = tid & 63, w = tid >> 6;
  int lrow = lane & 15, lk = (lane >> 4) * 8;
  f32x4 acc[2];
  acc[0] = (f32x4){0.f, 0.f, 0.f, 0.f};
  acc[1] = (f32x4){0.f, 0.f, 0.f, 0.f};
#pragma unroll
  for (int ks = 0; ks < 8; ++ks) {
    bf16x8 bfr = *(const bf16x8*)&Bs[(w * 16 + lrow) * 264 + ks * 32 + lk];
#pragma unroll
    for (int m = 0; m < 2; ++m) {
      bf16x8 af = *(const bf16x8*)&As[(m * 16 + lrow) * 264 + ks * 32 + lk];
      acc[m] = __builtin_amdgcn_mfma_f32_16x16x32_bf16(af, bfr, acc[m], 0, 0, 0);
    }
  }
  int col = nBase + w * 16 + (lane & 15);
  float bv = bias2[col];
  int orow = (lane >> 4) * 4;
#pragma unroll
  for (int m = 0; m < 2; ++m)
#pragma unroll
    for (int q = 0; q < 4; ++q) {
      int bb = m * 16 + orow + q;
      XW2[((size_t)t * 32 + bb) * G4 + col] = acc[m][q] + bv;
    }
}

__global__ __launch_bounds__(256) void gemms_kernel(
    const float* __restrict__ feat, const u16* __restrict__ w_ih1b,
    const float* __restrict__ bias1, float* __restrict__ X1,
    const u16* __restrict__ capb, const u16* __restrict__ w_ih2lb,
    const float* __restrict__ bias2, float* __restrict__ XW2) {
  __shared__ __align__(16) char smem[50688];
  int blk = blockIdx.x;
  if (blk < 160) {
    gemm_x1_body(smem, blk & 7, blk >> 3, feat, w_ih1b, bias1, X1);
  } else {
    int k = blk - 160;
    xw2_body(smem, k & 15, k >> 4, capb, w_ih2lb, bias2, XW2);
  }
}

// ===========================================================================
// Persistent recurrent kernel. 256 blocks x 256 threads (cooperative).
// Block (b, oct): j in [oct*32, oct*32+32), half-row split (192 weight VGPRs).
// Cross-block h exchange via SELF-VALIDATING packed f16x2 dwords: slots are
// pre-initialized to 0xFFFFFFFF (f16 NaN pair, unproducible by sigm*tanh);
// consumers poll the data itself -> ONE LLC round trip, no flags, no drains.
// Phase A (h1 chain, critical) publishes before Phase B (lstm2 + attention).
// ===========================================================================
struct RP {
  const float *X1, *XW2, *bias1, *bias2;
  const u16 *w_hh1h, *w_ih2rh, *w_hh2h;
  u32* H1H;     // [110][32][128] packed f16x2 of h1[T]
  u32* H2H;     // [110][32][128] packed f16x2 of h2[T]
  u16* H2NB;    // [29][32][256] bf16 decoder h2n
};

__global__ __launch_bounds__(256, 1) void recurrent_kernel(RP p) {
  __shared__ float encL[TE][257];             // 82 KB
  __shared__ __align__(16) f16x2 h1S[128], h2S[128];
  __shared__ float tmp2[256];
  __shared__ float gb1[128], gb2[128];
  __shared__ float hnew1[32], hnew2[32], cS1[32], cS2[32];
  __shared__ float sc[80];
  __shared__ float red[4];
  int bid = blockIdx.x, tid = threadIdx.x;
  int b = bid >> 3, oct = bid & 7;
  int r = tid >> 1, half = tid & 1;           // row in [0,128), k-half
  int gg_ = r >> 5, uu_ = r & 31;
  int grow = (gg_ << 8) + (oct << 5) + uu_;   // global gate row

  f16x2 wA[64], wB[64], wC[64];
  {
    const uint4* a4 = (const uint4*)(p.w_hh1h + (size_t)grow * 256 + half * 128);
    const uint4* b4 = (const uint4*)(p.w_ih2rh + (size_t)grow * 256 + half * 128);
    const uint4* c4 = (const uint4*)(p.w_hh2h + (size_t)grow * 256 + half * 128);
#pragma unroll
    for (int q = 0; q < 16; ++q) {
      uint4 ua = a4[q];
      wA[q * 4 + 0] = __builtin_bit_cast(f16x2, ua.x);
      wA[q * 4 + 1] = __builtin_bit_cast(f16x2, ua.y);
      wA[q * 4 + 2] = __builtin_bit_cast(f16x2, ua.z);
      wA[q * 4 + 3] = __builtin_bit_cast(f16x2, ua.w);
      uint4 ub = b4[q];
      wB[q * 4 + 0] = __builtin_bit_cast(f16x2, ub.x);
      wB[q * 4 + 1] = __builtin_bit_cast(f16x2, ub.y);
      wB[q * 4 + 2] = __builtin_bit_cast(f16x2, ub.z);
      wB[q * 4 + 3] = __builtin_bit_cast(f16x2, ub.w);
      uint4 uc = c4[q];
      wC[q * 4 + 0] = __builtin_bit_cast(f16x2, uc.x);
      wC[q * 4 + 1] = __builtin_bit_cast(f16x2, uc.y);
      wC[q * 4 + 2] = __builtin_bit_cast(f16x2, uc.z);
      wC[q * 4 + 3] = __builtin_bit_cast(f16x2, uc.w);
    }
  }
  float b1v[4], b2v[4];
  if (tid < 32) {
    int j = (oct << 5) + tid;
#pragma unroll
    for (int g2 = 0; g2 < 4; ++g2) {
      b1v[g2] = p.bias1[g2 * 256 + j];
      b2v[g2] = p.bias2[g2 * 256 + j];
    }
    cS1[tid] = 0.f;
    cS2[tid] = 0.f;
  }
  __syncthreads();

  for (int T = 0; T < 110; ++T) {
    // ---- x prefetch (issued early; completes under the polls) ----
    float x1v[4], x2v[4];
    if (tid < 32) {
      int j = (oct << 5) + tid;
#pragma unroll
      for (int g2 = 0; g2 < 4; ++g2) { x1v[g2] = b1v[g2]; x2v[g2] = b2v[g2]; }
      if (T < TE) {
        const float* xb = &p.X1[((size_t)b * TE + T) * G4 + j];
#pragma unroll
        for (int g2 = 0; g2 < 4; ++g2) x1v[g2] = xb[g2 * 256];
      }
      if (T >= 81) {
        const float* xb = &p.XW2[((size_t)(T - 81) * 32 + b) * G4 + j];
#pragma unroll
        for (int g2 = 0; g2 < 4; ++g2) x2v[g2] = xb[g2 * 256];
      }
    }
    // ================= PHASE A: lstm1 critical chain =================
    if (tid < 128) {
      const u32* src = &p.H1H[((size_t)T * 32 + b) * 128 + tid];
      u32 v = AT_LOAD(src);
      int gd = 0;
      while (v == SENT && ++gd < (1 << 24)) {
        __builtin_amdgcn_s_sleep(1);
        v = AT_LOAD(src);
      }
      h1S[tid] = __builtin_bit_cast(f16x2, v);
    }
    __syncthreads();
    {
      float a1 = 0.f;
      const uint4* h1v = ((const uint4*)h1S) + half * 16;
#pragma unroll
      for (int q = 0; q < 16; ++q) {
        uint4 uu = h1v[q];
        a1 = fdot2h(__builtin_bit_cast(f16x2, uu.x), wA[q * 4 + 0], a1);
        a1 = fdot2h(__builtin_bit_cast(f16x2, uu.y), wA[q * 4 + 1], a1);
        a1 = fdot2h(__builtin_bit_cast(f16x2, uu.z), wA[q * 4 + 2], a1);
        a1 = fdot2h(__builtin_bit_cast(f16x2, uu.w), wA[q * 4 + 3], a1);
      }
      a1 += __shfl_xor(a1, 1);
      if (half == 0) gb1[r] = a1;
    }
    __syncthreads();
    if (T <= 108) {
      if (tid < 32) {
        float gi = gb1[tid] + x1v[0];
        float gf = gb1[32 + tid] + x1v[1];
        float gG = gb1[64 + tid] + x1v[2];
        float go = gb1[96 + tid] + x1v[3];
        float c = sigm(gf) * cS1[tid] + sigm(gi) * tanhf(gG);
        cS1[tid] = c;
        hnew1[tid] = sigm(go) * tanhf(c);
      }
      if (tid < 16) {  // same wave as writers: lockstep-visible
        u32 pk = packh2(hnew1[2 * tid], hnew1[2 * tid + 1]);
        AT_STORE(&p.H1H[((size_t)(T + 1) * 32 + b) * 128 + (oct << 4) + tid], pk);
      }
    }
    // ================= PHASE B: lstm2 + attention (off-chain) =========
    if (T >= 1) {
      if (tid < 128) {
        const u32* src = &p.H2H[((size_t)(T - 1) * 32 + b) * 128 + tid];
        u32 v = AT_LOAD(src);
        int gd = 0;
        while (v == SENT && ++gd < (1 << 24)) {
          __builtin_amdgcn_s_sleep(1);
          v = AT_LOAD(src);
        }
        f16x2 hp = __builtin_bit_cast(f16x2, v);
        h2S[tid] = hp;
        tmp2[2 * tid] = (float)hp[0];
        tmp2[2 * tid + 1] = (float)hp[1];
      }
      __syncthreads();
      if (T >= 2 && T <= 81) encL[T - 2][tid] = tmp2[tid];
      if (T >= 82) {
        // attention: q = tmp2 (h2n[s-1]); parallel softmax
        float a = 0.f;
        if (tid < TE) {
          const float* e = &encL[tid][0];
#pragma unroll 8
          for (int k2 = 0; k2 < 256; ++k2) a += e[k2] * tmp2[k2];
        }
        float av = (tid < TE) ? a : -INFINITY;
#pragma unroll
        for (int d = 32; d; d >>= 1) av = fmaxf(av, __shfl_xor(av, d));
        if (tid == 0) red[0] = av;
        if (tid == 64) red[1] = av;
        __syncthreads();
        float m = fmaxf(red[0], red[1]);
        float e = (tid < TE) ? expf(a - m) : 0.f;
        float sv = e;
#pragma unroll
        for (int d = 32; d; d >>= 1) sv += __shfl_xor(sv, d);
        if (tid == 0) red[2] = sv;
        if (tid == 64) red[3] = sv;
        __syncthreads();
        float inv = 1.0f / (red[2] + red[3]);
        if (tid < TE) sc[tid] = e * inv;
        __syncthreads();
        float acc = 0.f;
        for (int t2 = 0; t2 < TE; ++t2) acc += sc[t2] * encL[t2][tid];
        tmp2[tid] = acc;
        __syncthreads();
        if (tid < 128)
          h2S[tid] = f16x2{(_Float16)tmp2[2 * tid], (_Float16)tmp2[2 * tid + 1]};
      }
      __syncthreads();
      // a2 = wB.h1 + wC.h2
      float a2 = 0.f;
      {
        const uint4* h1v = ((const uint4*)h1S) + half * 16;
        const uint4* h2v = ((const uint4*)h2S) + half * 16;
#pragma unroll
        for (int q = 0; q < 16; ++q) {
          uint4 uu = h1v[q];
          a2 = fdot2h(__builtin_bit_cast(f16x2, uu.x), wB[q * 4 + 0], a2);
          a2 = fdot2h(__builtin_bit_cast(f16x2, uu.y), wB[q * 4 + 1], a2);
          a2 = fdot2h(__builtin_bit_cast(f16x2, uu.z), wB[q * 4 + 2], a2);
          a2 = fdot2h(__builtin_bit_cast(f16x2, uu.w), wB[q * 4 + 3], a2);
        }
#pragma unroll
        for (int q = 0; q < 16; ++q) {
          uint4 uu = h2v[q];
          a2 = fdot2h(__builtin_bit_cast(f16x2, uu.x), wC[q * 4 + 0], a2);
          a2 = fdot2h(__builtin_bit_cast(f16x2, uu.y), wC[q * 4 + 1], a2);
          a2 = fdot2h(__builtin_bit_cast(f16x2, uu.z), wC[q * 4 + 2], a2);
          a2 = fdot2h(__builtin_bit_cast(f16x2, uu.w), wC[q * 4 + 3], a2);
        }
      }
      a2 += __shfl_xor(a2, 1);
      if (half == 0) gb2[r] = a2;
      __syncthreads();
      if (tid < 32) {
        float gi = gb2[tid] + x2v[0];
        float gf = gb2[32 + tid] + x2v[1];
        float gG = gb2[64 + tid] + x2v[2];
        float go = gb2[96 + tid] + x2v[3];
        float c = sigm(gf) * cS2[tid] + sigm(gi) * tanhf(gG);
        float h = sigm(go) * tanhf(c);
        cS2[tid] = c;
        hnew2[tid] = h;
        if (T >= 81)
          p.H2NB[((size_t)(T - 81) * 32 + b) * 256 + (oct << 5) + tid] = f2bf(h);
      }
      if (tid < 16) {
        u32 pk = packh2(hnew2[2 * tid], hnew2[2 * tid + 1]);
        AT_STORE(&p.H2H[((size_t)T * 32 + b) * 128 + (oct << 4) + tid], pk);
      }
    }
    __syncthreads();  // protect h1S/h2S/gb reuse next iteration
  }
}

// ===========================================================================
// Batched logits + fused CE partials: M=928, N=32000, K=256; A = H2NB bf16.
// ===========================================================================
__global__ __launch_bounds__(256, 1) void logits_ce_kernel(
    const u16* __restrict__ H2NB, const u16* __restrict__ wPK,
    const float* __restrict__ b_out, const int* __restrict__ targets,
    float* __restrict__ pmaxA, float* __restrict__ psumA,
    float* __restrict__ tgtv) {
  __shared__ __align__(16) u16 bS[32768];
  __shared__ __align__(16) u16 aS[32 * 264];
  __shared__ int tS[32];
  int tid = threadIdx.x, bid = blockIdx.x;
  const u16* src = wPK + (size_t)bid * 32768;
  for (int i = tid; i < 4096; i += 256)
    *(uint4*)&bS[i * 8] = *(const uint4*)&src[i * 8];
  int wid = tid >> 6, lane = tid & 63, lcol = lane & 15, lk = lane >> 4;
  float bo[2];
#pragma unroll
  for (int n = 0; n < 2; ++n) bo[n] = b_out[(bid * 8 + wid * 2 + n) * 16 + lcol];

  for (int rg = 0; rg < 29; ++rg) {
    __syncthreads();
    for (int i = tid; i < 1024; i += 256) {
      int r = i >> 5, c8 = i & 31;
      *(uint4*)&aS[r * 264 + c8 * 8] =
          *(const uint4*)&H2NB[(size_t)rg * 8192 + r * 256 + c8 * 8];
    }
    if (tid < 32) tS[tid] = targets[rg * 32 + tid];
    __syncthreads();
    f32x4 acc[2][2];
#pragma unroll
    for (int m = 0; m < 2; ++m)
#pragma unroll
      for (int n = 0; n < 2; ++n) acc[m][n] = (f32x4){0.f, 0.f, 0.f, 0.f};
#pragma unroll
    for (int ks = 0; ks < 8; ++ks) {
      bf16x8 a0 = *(const bf16x8*)&aS[lcol * 264 + ks * 32 + lk * 8];
      bf16x8 a1 = *(const bf16x8*)&aS[(16 + lcol) * 264 + ks * 32 + lk * 8];
      bf16x8 b0 = *(const bf16x8*)&bS[(wid * 2) * 4096 + ((ks * 4 + lk) * 16 + lcol) * 8];
      bf16x8 b1 = *(const bf16x8*)&bS[(wid * 2 + 1) * 4096 + ((ks * 4 + lk) * 16 + lcol) * 8];
      acc[0][0] = __builtin_amdgcn_mfma_f32_16x16x32_bf16(a0, b0, acc[0][0], 0, 0, 0);
      acc[0][1] = __builtin_amdgcn_mfma_f32_16x16x32_bf16(a0, b1, acc[0][1], 0, 0, 0);
      acc[1][0] = __builtin_amdgcn_mfma_f32_16x16x32_bf16(a1, b0, acc[1][0], 0, 0, 0);
      acc[1][1] = __builtin_amdgcn_mfma_f32_16x16x32_bf16(a1, b1, acc[1][1], 0, 0, 0);
    }
    int nbase = (bid * 8 + wid * 2) * 16 + lcol;
#pragma unroll
    for (int m = 0; m < 2; ++m) {
      float pm[4], psv[4];
#pragma unroll
      for (int q = 0; q < 4; ++q) {
        float v0 = acc[m][0][q] + bo[0];
        float v1 = acc[m][1][q] + bo[1];
        int r = m * 16 + lk * 4 + q;
        int tg = tS[r];
        if (tg == nbase) tgtv[rg * 32 + r] = v0;
        if (tg == nbase + 16) tgtv[rg * 32 + r] = v1;
        float mx = fmaxf(v0, v1);
#pragma unroll
        for (int d = 1; d < 16; d <<= 1) mx = fmaxf(mx, __shfl_xor(mx, d));
        float e = expf(v0 - mx) + expf(v1 - mx);
#pragma unroll
        for (int d = 1; d < 16; d <<= 1) e += __shfl_xor(e, d);
        pm[q] = mx;
        psv[q] = e;
      }
      if (lcol == 0) {
        int chunk = bid * 4 + wid;
#pragma unroll
        for (int q = 0; q < 4; ++q) {
          int r2 = rg * 32 + m * 16 + lk * 4 + q;
          pmaxA[(size_t)r2 * 1000 + chunk] = pm[q];
          psumA[(size_t)r2 * 1000 + chunk] = psv[q];
        }
      }
    }
  }
}

// one block per row; last finishing block writes the output (no extra launch)
__global__ __launch_bounds__(256) void ce_final_kernel(
    const float* __restrict__ pmaxA, const float* __restrict__ psumA,
    const float* __restrict__ tgtv, float* __restrict__ loss,
    int* __restrict__ cectr, float* __restrict__ out) {
  int row = blockIdx.x;
  int tid = threadIdx.x;
  const float* pm = pmaxA + (size_t)row * 1000;
  const float* psv = psumA + (size_t)row * 1000;
  __shared__ float sm[256];
  float m = -INFINITY;
  for (int c = tid; c < 1000; c += 256) m = fmaxf(m, pm[c]);
  sm[tid] = m;
  __syncthreads();
  for (int off = 128; off; off >>= 1) {
    if (tid < off) sm[tid] = fmaxf(sm[tid], sm[tid + off]);
    __syncthreads();
  }
  float M = sm[0];
  __syncthreads();
  float s = 0.f;
  for (int c = tid; c < 1000; c += 256) s += psv[c] * expf(pm[c] - M);
  sm[tid] = s;
  __syncthreads();
  for (int off = 128; off; off >>= 1) {
    if (tid < off) sm[tid] += sm[tid + off];
    __syncthreads();
  }
  if (tid == 0) {
    atomicAdd(loss, (M + logf(sm[0]) - tgtv[row]) * (1.0f / 1024.0f));
    asm volatile("s_waitcnt vmcnt(0)" ::: "memory");  // loss-add at LLC first
    int old = __hip_atomic_fetch_add(cectr, 1, __ATOMIC_ACQ_REL, __HIP_MEMORY_SCOPE_AGENT);
    if (old == 927) out[0] = AT_LOAD(loss);
  }
}

// ---------------------------------------------------------------------------
extern "C" void kernel_launch(void* const* d_in, const int* in_sizes, int n_in,
                              void* d_out, int out_size, void* d_ws, size_t ws_size,
                              hipStream_t stream) {
  (void)in_sizes; (void)n_in; (void)out_size; (void)ws_size;
  const float* feat    = (const float*)d_in[0];
  const float* caption = (const float*)d_in[1];
  const float* onehot  = (const float*)d_in[2];
  const float* w_ih1   = (const float*)d_in[4];
  const float* w_hh1   = (const float*)d_in[5];
  const float* b_ih1   = (const float*)d_in[6];
  const float* b_hh1   = (const float*)d_in[7];
  const float* w_ih2   = (const float*)d_in[8];
  const float* w_hh2   = (const float*)d_in[9];
  const float* b_ih2   = (const float*)d_in[10];
  const float* b_hh2   = (const float*)d_in[11];
  const float* w_out   = (const float*)d_in[12];
  const float* b_out   = (const float*)d_in[13];

  char* p = (char*)d_ws;
  auto alloc = [&](size_t bytes) {
    char* r = p;
    p += (bytes + 255) & ~(size_t)255;
    return r;
  };
  float* X1      = (float*)alloc(2560ull * 1024 * 4);      // 10.5 MB
  float* XW2     = (float*)alloc(29ull * 32 * 1024 * 4);   // 3.8 MB
  float* bias1   = (float*)alloc(1024 * 4);
  float* bias2   = (float*)alloc(1024 * 4);
  u32*   H1H     = (u32*)alloc(110ull * 32 * 128 * 4);     // 1.8 MB
  u32*   H2H     = (u32*)alloc(110ull * 32 * 128 * 4);     // 1.8 MB
  u16*   H2NB    = (u16*)alloc(29ull * 8192 * 2);
  float* pmaxA   = (float*)alloc(928ull * 1000 * 4);
  float* psumA   = (float*)alloc(928ull * 1000 * 4);
  float* tgtv    = (float*)alloc(928 * 4);
  float* lossacc = (float*)alloc(256);
  int*   cectr   = (int*)alloc(256);
  int*   targets = (int*)alloc(29 * 32 * 4);
  u16*   w_ih1b  = (u16*)alloc(1024ull * 4096 * 2);        // 8.4 MB
  u16*   w_ih2lb = (u16*)alloc(1024ull * 256 * 2);
  u16*   capb    = (u16*)alloc(32ull * 30 * 256 * 2);
  u16*   w_hh1h  = (u16*)alloc(1024ull * 256 * 2);
  u16*   w_hh2h  = (u16*)alloc(1024ull * 256 * 2);
  u16*   w_ih2rh = (u16*)alloc(1024ull * 256 * 2);
  u16*   wPK     = (u16*)alloc(2000ull * 32 * 16 * 8 * 2); // 16.4 MB

  prep_kernel<<<10728, 256, 0, stream>>>(
      w_ih1, w_out, w_ih2, caption, onehot, w_hh1, w_hh2,
      b_ih1, b_hh1, b_ih2, b_hh2,
      w_ih1b, wPK, w_ih2lb, capb, w_hh1h, w_hh2h, w_ih2rh,
      bias1, bias2, H1H, H2H, lossacc, cectr, targets);
  gemms_kernel<<<624, 256, 0, stream>>>(feat, w_ih1b, bias1, X1,
                                        capb, w_ih2lb, bias2, XW2);

  RP rp;
  rp.X1 = X1; rp.XW2 = XW2; rp.bias1 = bias1; rp.bias2 = bias2;
  rp.w_hh1h = w_hh1h; rp.w_ih2rh = w_ih2rh; rp.w_hh2h = w_hh2h;
  rp.H1H = H1H; rp.H2H = H2H; rp.H2NB = H2NB;
  void* args[] = {&rp};
  hipLaunchCooperativeKernel((const void*)recurrent_kernel, dim3(256), dim3(256),
                             args, 0, stream);

  logits_ce_kernel<<<250, 256, 0, stream>>>(H2NB, wPK, b_out, targets, pmaxA, psumA, tgtv);
  ce_final_kernel<<<928, 256, 0, stream>>>(pmaxA, psumA, tgtv, lossacc, cectr,
                                           (float*)d_out);
}

// Round 10
// 735.897 us; speedup vs baseline: 4.1682x; 1.2650x over previous
//
#include <hip/hip_runtime.h>
#include <hip/hip_bf16.h>
#include <math.h>

// Problem dims
#define BB 32
#define TE 80
#define FEAT 4096
#define HH 256
#define W2V 256
#define TD 30
#define VV 32000
#define G4 1024   // 4*H

typedef unsigned short u16;
typedef unsigned int u32;
using f32x4 = __attribute__((ext_vector_type(4))) float;
using bf16x8 = __attribute__((ext_vector_type(8))) short;
using f16x2 = __attribute__((ext_vector_type(2))) _Float16;

#define SENT 0xFFFFFFFFu

__device__ __forceinline__ float sigm(float x) { return 1.0f / (1.0f + expf(-x)); }
__device__ __forceinline__ u16 f2bf(float f) {
  u32 u = __float_as_uint(f);
  u32 r = (u + 0x7FFFu + ((u >> 16) & 1u)) >> 16;
  return (u16)r;
}
__device__ __forceinline__ u32 packh2(float lo, float hi) {
  f16x2 v = {(_Float16)lo, (_Float16)hi};
  return __builtin_bit_cast(u32, v);
}

#define AT_LOAD(p)     __hip_atomic_load((p), __ATOMIC_RELAXED, __HIP_MEMORY_SCOPE_AGENT)
#define AT_STORE(p, v) __hip_atomic_store((p), (v), __ATOMIC_RELAXED, __HIP_MEMORY_SCOPE_AGENT)

__device__ __forceinline__ float fdot2h(f16x2 a, f16x2 b, float c) {
#if __has_builtin(__builtin_amdgcn_fdot2)
  return __builtin_amdgcn_fdot2(a, b, c, false);
#else
  return c + (float)a[0] * (float)b[0] + (float)a[1] * (float)b[1];
#endif
}

// ===========================================================================
// prep: one-time elementwise work + FULL sentinel init + argmax, one launch.
// ===========================================================================
__global__ __launch_bounds__(256) void prep_kernel(
    const float* __restrict__ w_ih1, const float* __restrict__ w_out,
    const float* __restrict__ w_ih2, const float* __restrict__ caption,
    const float* __restrict__ onehot,
    const float* __restrict__ b_ih1, const float* __restrict__ b_hh1,
    const float* __restrict__ b_ih2, const float* __restrict__ b_hh2,
    u16* __restrict__ w_ih1b, u16* __restrict__ wPK,
    u16* __restrict__ w_ih2lb, u16* __restrict__ capb,
    float* __restrict__ bias1, float* __restrict__ bias2,
    u32* __restrict__ H1H, u32* __restrict__ H2H,
    float* __restrict__ loss, int* __restrict__ cectr,
    int* __restrict__ targets) {
  int blk = blockIdx.x, tid = threadIdx.x;
  if (blk < 4096) {
    int i = blk * 256 + tid;
    float4 v = *(const float4*)&w_ih1[(size_t)i * 4];
    *(ushort4*)&w_ih1b[(size_t)i * 4] =
        make_ushort4(f2bf(v.x), f2bf(v.y), f2bf(v.z), f2bf(v.w));
  } else if (blk < 8096) {
    int i = (blk - 4096) * 256 + tid;  // (n, kg)
    int n = i >> 5, kg = i & 31;
    float4 v0 = *(const float4*)&w_out[(size_t)n * 256 + kg * 8];
    float4 v1 = *(const float4*)&w_out[(size_t)n * 256 + kg * 8 + 4];
    size_t dst = ((size_t)((n >> 4) * 32 + kg) * 16 + (n & 15)) * 8;
    *(ushort4*)&wPK[dst] = make_ushort4(f2bf(v0.x), f2bf(v0.y), f2bf(v0.z), f2bf(v0.w));
    *(ushort4*)&wPK[dst + 4] = make_ushort4(f2bf(v1.x), f2bf(v1.y), f2bf(v1.z), f2bf(v1.w));
  } else if (blk < 8352) {
    int i = (blk - 8096) * 256 + tid;
    int row = i >> 6, c = i & 63;
    float4 v = *(const float4*)&w_ih2[(size_t)row * 512 + c * 4];
    *(ushort4*)&w_ih2lb[(size_t)row * 256 + c * 4] =
        make_ushort4(f2bf(v.x), f2bf(v.y), f2bf(v.z), f2bf(v.w));
  } else if (blk < 8592) {
    int i = (blk - 8352) * 256 + tid;
    float4 v = *(const float4*)&caption[(size_t)i * 4];
    *(ushort4*)&capb[(size_t)i * 4] =
        make_ushort4(f2bf(v.x), f2bf(v.y), f2bf(v.z), f2bf(v.w));
  } else if (blk < 10352) {
    int i = (blk - 8592) * 256 + tid;  // < 450560 = 110*32*128
    u32 v = (i < 4096) ? 0u : SENT;    // slot T=0 = packed f16 zeros
    H1H[i] = v;
    H2H[i] = v;
    if (i < 1024) {
      bias1[i] = b_ih1[i] + b_hh1[i];
      bias2[i] = b_ih2[i] + b_hh2[i];
    }
    if (i == 0) { *loss = 0.0f; *cectr = 0; }
  } else {
    int k = blk - 10352;  // (s-1)*32 + b
    int s = (k >> 5) + 1, b = k & 31;
    const float* row = &onehot[((size_t)b * TD + s) * VV];
    float bv = -INFINITY;
    int bi = 0x7fffffff;
    for (int v = tid; v < VV; v += 256) {
      float x = row[v];
      if (x > bv || (x == bv && v < bi)) { bv = x; bi = v; }
    }
    __shared__ float sv[256];
    __shared__ int si[256];
    sv[tid] = bv; si[tid] = bi;
    __syncthreads();
    for (int off = 128; off; off >>= 1) {
      if (tid < off) {
        float ov = sv[tid + off]; int oi = si[tid + off];
        if (ov > sv[tid] || (ov == sv[tid] && oi < si[tid])) { sv[tid] = ov; si[tid] = oi; }
      }
      __syncthreads();
    }
    if (tid == 0) targets[k] = si[0];
  }
}

// ===========================================================================
// Fused one-time GEMMs: blocks [0,160) = X1 MFMA GEMM; [160,624) = XW2.
// ===========================================================================
#define GBM 128
#define GBN 128
#define GBK 64
#define LDSTR 72

__device__ void gemm_x1_body(char* smem, int bx, int by,
                             const float* __restrict__ A, const u16* __restrict__ Bw,
                             const float* __restrict__ bias, float* __restrict__ C) {
  u16* As = (u16*)smem;
  u16* Bs = (u16*)(smem + 18432);
  int tid = threadIdx.x;
  int rBase = by * GBM;
  int nBase = bx * GBN;
  int lane = tid & 63, w = tid >> 6;
  int wrow = (w >> 1) * 64, wcol = (w & 1) * 64;
  int lrow = lane & 15, lk = (lane >> 4) * 8;

  f32x4 acc[4][4];
#pragma unroll
  for (int m = 0; m < 4; ++m)
#pragma unroll
    for (int n = 0; n < 4; ++n) acc[m][n] = (f32x4){0.f, 0.f, 0.f, 0.f};

  for (int k0 = 0; k0 < FEAT; k0 += GBK) {
#pragma unroll
    for (int i = 0; i < 8; ++i) {
      int f = i * 256 + tid;
      int r = f >> 4, c = (f & 15) << 2;
      float4 v = *(const float4*)&A[(size_t)(rBase + r) * FEAT + k0 + c];
      *(ushort4*)&As[r * LDSTR + c] =
          make_ushort4(f2bf(v.x), f2bf(v.y), f2bf(v.z), f2bf(v.w));
    }
#pragma unroll
    for (int i = 0; i < 4; ++i) {
      int f = i * 256 + tid;
      int r = f >> 3, c = (f & 7) << 3;
      uint4 v = *(const uint4*)&Bw[(size_t)(nBase + r) * FEAT + k0 + c];
      *(uint4*)&Bs[r * LDSTR + c] = v;
    }
    __syncthreads();
#pragma unroll
    for (int s2 = 0; s2 < 2; ++s2) {
      bf16x8 af[4], bfr[4];
#pragma unroll
      for (int m = 0; m < 4; ++m)
        af[m] = *(const bf16x8*)&As[(wrow + m * 16 + lrow) * LDSTR + s2 * 32 + lk];
#pragma unroll
      for (int n = 0; n < 4; ++n)
        bfr[n] = *(const bf16x8*)&Bs[(wcol + n * 16 + lrow) * LDSTR + s2 * 32 + lk];
#pragma unroll
      for (int m = 0; m < 4; ++m)
#pragma unroll
        for (int n = 0; n < 4; ++n)
          acc[m][n] = __builtin_amdgcn_mfma_f32_16x16x32_bf16(
              af[m], bfr[n], acc[m][n], 0, 0, 0);
    }
    __syncthreads();
  }
  int orow = (lane >> 4) * 4;
  int ocol = lane & 15;
#pragma unroll
  for (int m = 0; m < 4; ++m)
#pragma unroll
    for (int n = 0; n < 4; ++n) {
      int cidx = nBase + wcol + n * 16 + ocol;
      float bv = bias[cidx];
#pragma unroll
      for (int q = 0; q < 4; ++q) {
        int r = rBase + wrow + m * 16 + orow + q;
        C[(size_t)r * G4 + cidx] = acc[m][n][q] + bv;
      }
    }
}

__device__ void xw2_body(char* smem, int nb, int t,
                         const u16* __restrict__ capb, const u16* __restrict__ w_ih2lb,
                         const float* __restrict__ bias2, float* __restrict__ XW2) {
  u16* As = (u16*)smem;
  u16* Bs = (u16*)(smem + 16896);
  int tid = threadIdx.x;
  int nBase = nb * 64;
#pragma unroll
  for (int it = 0; it < 4; ++it) {
    int i = it * 256 + tid;
    int r = i >> 5, c8 = i & 31;
    *(uint4*)&As[r * 264 + c8 * 8] =
        *(const uint4*)&capb[((size_t)r * TD + t) * 256 + c8 * 8];
  }
#pragma unroll
  for (int it = 0; it < 8; ++it) {
    int i = it * 256 + tid;
    int r = i >> 5, c8 = i & 31;
    *(uint4*)&Bs[r * 264 + c8 * 8] =
        *(const uint4*)&w_ih2lb[(size_t)(nBase + r) * 256 + c8 * 8];
  }
  __syncthreads();
  int lane = tid & 63, w = tid >> 6;
  int lrow = lane & 15, lk = (lane >> 4) * 8;
  f32x4 acc[2];
  acc[0] = (f32x4){0.f, 0.f, 0.f, 0.f};
  acc[1] = (f32x4){0.f, 0.f, 0.f, 0.f};
#pragma unroll
  for (int ks = 0; ks < 8; ++ks) {
    bf16x8 bfr = *(const bf16x8*)&Bs[(w * 16 + lrow) * 264 + ks * 32 + lk];
#pragma unroll
    for (int m = 0; m < 2; ++m) {
      bf16x8 af = *(const bf16x8*)&As[(m * 16 + lrow) * 264 + ks * 32 + lk];
      acc[m] = __builtin_amdgcn_mfma_f32_16x16x32_bf16(af, bfr, acc[m], 0, 0, 0);
    }
  }
  int col = nBase + w * 16 + (lane & 15);
  float bv = bias2[col];
  int orow = (lane >> 4) * 4;
#pragma unroll
  for (int m = 0; m < 2; ++m)
#pragma unroll
    for (int q = 0; q < 4; ++q) {
      int bb = m * 16 + orow + q;
      XW2[((size_t)t * 32 + bb) * G4 + col] = acc[m][q] + bv;
    }
}

__global__ __launch_bounds__(256) void gemms_kernel(
    const float* __restrict__ feat, const u16* __restrict__ w_ih1b,
    const float* __restrict__ bias1, float* __restrict__ X1,
    const u16* __restrict__ capb, const u16* __restrict__ w_ih2lb,
    const float* __restrict__ bias2, float* __restrict__ XW2) {
  __shared__ __align__(16) char smem[50688];
  int blk = blockIdx.x;
  if (blk < 160) {
    gemm_x1_body(smem, blk & 7, blk >> 3, feat, w_ih1b, bias1, X1);
  } else {
    int k = blk - 160;
    xw2_body(smem, k & 15, k >> 4, capb, w_ih2lb, bias2, XW2);
  }
}

// ===========================================================================
// Persistent recurrent kernel. 256 blocks x 512 threads (cooperative).
// Role split: blocks [0,128) = L1 (h1 chain only); [128,256) = L2B (h2 chain,
// encL history, attention, H2NB). Block (b, q) owns j in [q*64,(q+1)*64) for
// all 4 gates. Thread = (row r2 in [0,256), k-half). Weights in registers:
// L1: 64 f16x2 (wA half-row); L2B: 128 f16x2 (wB+wC half-rows); converted
// f32->f16 in-kernel at startup. Self-validating sentinel exchange (ALL slots
// initialized): one LLC round trip per chain step, chains overlap.
// ===========================================================================
struct RP {
  const float *X1, *XW2, *bias1, *bias2;
  const float *w_hh1, *w_ih2, *w_hh2;
  u32* H1H;     // [110][32][128] packed f16x2 of h1[T]
  u32* H2H;     // [110][32][128] packed f16x2 of h2[U]
  u16* H2NB;    // [29][32][256] bf16 decoder h2n
};

__global__ __launch_bounds__(512, 1) void recurrent_kernel(RP p) {
  __shared__ float encL[TE][257];             // 82 KB (L2B only)
  __shared__ __align__(16) f16x2 h1S[128], h2S[128];
  __shared__ float tmp2[256];
  __shared__ float gb[256];
  __shared__ float hnew[64];
  __shared__ float sc[80];
  __shared__ float red[4];
  int bid = blockIdx.x, tid = threadIdx.x;
  bool isL1 = bid < 128;
  int lb = isL1 ? bid : bid - 128;
  int b = lb >> 2, q = lb & 3;
  int r2 = tid >> 1, half = tid & 1;          // row in [0,256), k-half
  int g = r2 >> 6, jj = r2 & 63;
  int grow = (g << 8) + (q << 6) + jj;        // global gate row
  bool fin = (half == 0) && (r2 < 64);        // finalize lanes: j = q*64 + r2
  int jfin = (q << 6) + (r2 & 63);

  if (isL1) {
    // ---- wA = w_hh1 half-row, f32 -> f16 in-register ----
    f16x2 wA[64];
    {
      const float4* s4 = (const float4*)(p.w_hh1 + (size_t)grow * 256 + half * 128);
#pragma unroll
      for (int k = 0; k < 32; ++k) {
        float4 v = s4[k];
        wA[k * 2 + 0] = f16x2{(_Float16)v.x, (_Float16)v.y};
        wA[k * 2 + 1] = f16x2{(_Float16)v.z, (_Float16)v.w};
      }
    }
    float c1 = 0.f;
    float b1v[4];
    if (fin) {
#pragma unroll
      for (int g2 = 0; g2 < 4; ++g2) b1v[g2] = p.bias1[g2 * 256 + jfin];
    }
    __syncthreads();
    for (int T = 0; T < 109; ++T) {
      float x1v[4];
      if (fin) {
        if (T < TE) {
          const float* xb = &p.X1[((size_t)b * TE + T) * G4 + jfin];
#pragma unroll
          for (int g2 = 0; g2 < 4; ++g2) x1v[g2] = xb[g2 * 256];
        } else {
#pragma unroll
          for (int g2 = 0; g2 < 4; ++g2) x1v[g2] = b1v[g2];
        }
      }
      if (tid < 128) {
        const u32* src = &p.H1H[((size_t)T * 32 + b) * 128 + tid];
        u32 v = AT_LOAD(src);
        int gd = 0;
        while (v == SENT && ++gd < (1 << 24)) {
          __builtin_amdgcn_s_sleep(1);
          v = AT_LOAD(src);
        }
        h1S[tid] = __builtin_bit_cast(f16x2, v);
      }
      __syncthreads();
      float a1 = 0.f;
      {
        const uint4* hv = ((const uint4*)h1S) + half * 16;
#pragma unroll
        for (int k = 0; k < 16; ++k) {
          uint4 uu = hv[k];
          a1 = fdot2h(__builtin_bit_cast(f16x2, uu.x), wA[k * 4 + 0], a1);
          a1 = fdot2h(__builtin_bit_cast(f16x2, uu.y), wA[k * 4 + 1], a1);
          a1 = fdot2h(__builtin_bit_cast(f16x2, uu.z), wA[k * 4 + 2], a1);
          a1 = fdot2h(__builtin_bit_cast(f16x2, uu.w), wA[k * 4 + 3], a1);
        }
      }
      a1 += __shfl_xor(a1, 1);
      if (half == 0) gb[r2] = a1;
      __syncthreads();
      if (fin) {
        int u = r2;
        float gi = gb[u] + x1v[0];
        float gf = gb[64 + u] + x1v[1];
        float gG = gb[128 + u] + x1v[2];
        float go = gb[192 + u] + x1v[3];
        c1 = sigm(gf) * c1 + sigm(gi) * tanhf(gG);
        hnew[u] = sigm(go) * tanhf(c1);
      }
      __syncthreads();
      if (tid < 32) {
        u32 pk = packh2(hnew[2 * tid], hnew[2 * tid + 1]);
        AT_STORE(&p.H1H[((size_t)(T + 1) * 32 + b) * 128 + (q << 5) + tid], pk);
      }
    }
  } else {
    // ---- wB = w_ih2[:,256:512] half-row; wC = w_hh2 half-row ----
    f16x2 wB[64], wC[64];
    {
      const float4* sB = (const float4*)(p.w_ih2 + (size_t)grow * 512 + 256 + half * 128);
      const float4* sC = (const float4*)(p.w_hh2 + (size_t)grow * 256 + half * 128);
#pragma unroll
      for (int k = 0; k < 32; ++k) {
        float4 v = sB[k];
        wB[k * 2 + 0] = f16x2{(_Float16)v.x, (_Float16)v.y};
        wB[k * 2 + 1] = f16x2{(_Float16)v.z, (_Float16)v.w};
        float4 u = sC[k];
        wC[k * 2 + 0] = f16x2{(_Float16)u.x, (_Float16)u.y};
        wC[k * 2 + 1] = f16x2{(_Float16)u.z, (_Float16)u.w};
      }
    }
    float c2 = 0.f;
    float b2v[4];
    if (fin) {
#pragma unroll
      for (int g2 = 0; g2 < 4; ++g2) b2v[g2] = p.bias2[g2 * 256 + jfin];
    }
    __syncthreads();
    for (int U = 1; U <= 109; ++U) {
      float x2v[4];
      if (fin) {
        if (U <= TE) {
#pragma unroll
          for (int g2 = 0; g2 < 4; ++g2) x2v[g2] = b2v[g2];
        } else {
          const float* xb = &p.XW2[((size_t)(U - 81) * 32 + b) * G4 + jfin];
#pragma unroll
          for (int g2 = 0; g2 < 4; ++g2) x2v[g2] = xb[g2 * 256];
        }
      }
      // concurrent polls: h1[U] and h2[U-1]
      if (tid < 128) {
        const u32* src = &p.H1H[((size_t)U * 32 + b) * 128 + tid];
        u32 v = AT_LOAD(src);
        int gd = 0;
        while (v == SENT && ++gd < (1 << 24)) {
          __builtin_amdgcn_s_sleep(1);
          v = AT_LOAD(src);
        }
        h1S[tid] = __builtin_bit_cast(f16x2, v);
      } else if (tid < 256) {
        int t2 = tid - 128;
        const u32* src = &p.H2H[((size_t)(U - 1) * 32 + b) * 128 + t2];
        u32 v = AT_LOAD(src);
        int gd = 0;
        while (v == SENT && ++gd < (1 << 24)) {
          __builtin_amdgcn_s_sleep(1);
          v = AT_LOAD(src);
        }
        f16x2 hp = __builtin_bit_cast(f16x2, v);
        h2S[t2] = hp;
        tmp2[2 * t2] = (float)hp[0];
        tmp2[2 * t2 + 1] = (float)hp[1];
      }
      __syncthreads();
      if (U <= 81) {
        if (U >= 2 && tid < 256) encL[U - 2][tid] = tmp2[tid];
      } else {
        // attention: q-vec = tmp2 (h2n[s-1]); parallel softmax; ctx -> h2S
        float a = 0.f;
        if (tid < TE) {
          const float* e = &encL[tid][0];
#pragma unroll 8
          for (int k2 = 0; k2 < 256; ++k2) a += e[k2] * tmp2[k2];
        }
        float av = (tid < TE) ? a : -INFINITY;
#pragma unroll
        for (int d = 32; d; d >>= 1) av = fmaxf(av, __shfl_xor(av, d));
        if (tid == 0) red[0] = av;
        if (tid == 64) red[1] = av;
        __syncthreads();
        float m = fmaxf(red[0], red[1]);
        float e = (tid < TE) ? expf(a - m) : 0.f;
        float sv = e;
#pragma unroll
        for (int d = 32; d; d >>= 1) sv += __shfl_xor(sv, d);
        if (tid == 0) red[2] = sv;
        if (tid == 64) red[3] = sv;
        __syncthreads();
        float inv = 1.0f / (red[2] + red[3]);
        if (tid < TE) sc[tid] = e * inv;
        __syncthreads();
        if (tid < 256) {
          float acc = 0.f;
          for (int t2 = 0; t2 < TE; ++t2) acc += sc[t2] * encL[t2][tid];
          tmp2[tid] = acc;
        }
        __syncthreads();
        if (tid < 128)
          h2S[tid] = f16x2{(_Float16)tmp2[2 * tid], (_Float16)tmp2[2 * tid + 1]};
      }
      __syncthreads();
      float a2 = 0.f;
      {
        const uint4* h1v = ((const uint4*)h1S) + half * 16;
        const uint4* h2v = ((const uint4*)h2S) + half * 16;
#pragma unroll
        for (int k = 0; k < 16; ++k) {
          uint4 uu = h1v[k];
          a2 = fdot2h(__builtin_bit_cast(f16x2, uu.x), wB[k * 4 + 0], a2);
          a2 = fdot2h(__builtin_bit_cast(f16x2, uu.y), wB[k * 4 + 1], a2);
          a2 = fdot2h(__builtin_bit_cast(f16x2, uu.z), wB[k * 4 + 2], a2);
          a2 = fdot2h(__builtin_bit_cast(f16x2, uu.w), wB[k * 4 + 3], a2);
        }
#pragma unroll
        for (int k = 0; k < 16; ++k) {
          uint4 uu = h2v[k];
          a2 = fdot2h(__builtin_bit_cast(f16x2, uu.x), wC[k * 4 + 0], a2);
          a2 = fdot2h(__builtin_bit_cast(f16x2, uu.y), wC[k * 4 + 1], a2);
          a2 = fdot2h(__builtin_bit_cast(f16x2, uu.z), wC[k * 4 + 2], a2);
          a2 = fdot2h(__builtin_bit_cast(f16x2, uu.w), wC[k * 4 + 3], a2);
        }
      }
      a2 += __shfl_xor(a2, 1);
      if (half == 0) gb[r2] = a2;
      __syncthreads();
      if (fin) {
        int u = r2;
        float gi = gb[u] + x2v[0];
        float gf = gb[64 + u] + x2v[1];
        float gG = gb[128 + u] + x2v[2];
        float go = gb[192 + u] + x2v[3];
        c2 = sigm(gf) * c2 + sigm(gi) * tanhf(gG);
        float h = sigm(go) * tanhf(c2);
        hnew[u] = h;
        if (U >= 81)
          p.H2NB[((size_t)(U - 81) * 32 + b) * 256 + jfin] = f2bf(h);
      }
      __syncthreads();
      if (tid < 32) {
        u32 pk = packh2(hnew[2 * tid], hnew[2 * tid + 1]);
        AT_STORE(&p.H2H[((size_t)U * 32 + b) * 128 + (q << 5) + tid], pk);
      }
    }
  }
}

// ===========================================================================
// Batched logits + fused CE partials: M=928, N=32000, K=256; A = H2NB bf16.
// ===========================================================================
__global__ __launch_bounds__(256, 1) void logits_ce_kernel(
    const u16* __restrict__ H2NB, const u16* __restrict__ wPK,
    const float* __restrict__ b_out, const int* __restrict__ targets,
    float* __restrict__ pmaxA, float* __restrict__ psumA,
    float* __restrict__ tgtv) {
  __shared__ __align__(16) u16 bS[32768];
  __shared__ __align__(16) u16 aS[32 * 264];
  __shared__ int tS[32];
  int tid = threadIdx.x, bid = blockIdx.x;
  const u16* src = wPK + (size_t)bid * 32768;
  for (int i = tid; i < 4096; i += 256)
    *(uint4*)&bS[i * 8] = *(const uint4*)&src[i * 8];
  int wid = tid >> 6, lane = tid & 63, lcol = lane & 15, lk = lane >> 4;
  float bo[2];
#pragma unroll
  for (int n = 0; n < 2; ++n) bo[n] = b_out[(bid * 8 + wid * 2 + n) * 16 + lcol];

  for (int rg = 0; rg < 29; ++rg) {
    __syncthreads();
    for (int i = tid; i < 1024; i += 256) {
      int r = i >> 5, c8 = i & 31;
      *(uint4*)&aS[r * 264 + c8 * 8] =
          *(const uint4*)&H2NB[(size_t)rg * 8192 + r * 256 + c8 * 8];
    }
    if (tid < 32) tS[tid] = targets[rg * 32 + tid];
    __syncthreads();
    f32x4 acc[2][2];
#pragma unroll
    for (int m = 0; m < 2; ++m)
#pragma unroll
      for (int n = 0; n < 2; ++n) acc[m][n] = (f32x4){0.f, 0.f, 0.f, 0.f};
#pragma unroll
    for (int ks = 0; ks < 8; ++ks) {
      bf16x8 a0 = *(const bf16x8*)&aS[lcol * 264 + ks * 32 + lk * 8];
      bf16x8 a1 = *(const bf16x8*)&aS[(16 + lcol) * 264 + ks * 32 + lk * 8];
      bf16x8 b0 = *(const bf16x8*)&bS[(wid * 2) * 4096 + ((ks * 4 + lk) * 16 + lcol) * 8];
      bf16x8 b1 = *(const bf16x8*)&bS[(wid * 2 + 1) * 4096 + ((ks * 4 + lk) * 16 + lcol) * 8];
      acc[0][0] = __builtin_amdgcn_mfma_f32_16x16x32_bf16(a0, b0, acc[0][0], 0, 0, 0);
      acc[0][1] = __builtin_amdgcn_mfma_f32_16x16x32_bf16(a0, b1, acc[0][1], 0, 0, 0);
      acc[1][0] = __builtin_amdgcn_mfma_f32_16x16x32_bf16(a1, b0, acc[1][0], 0, 0, 0);
      acc[1][1] = __builtin_amdgcn_mfma_f32_16x16x32_bf16(a1, b1, acc[1][1], 0, 0, 0);
    }
    int nbase = (bid * 8 + wid * 2) * 16 + lcol;
#pragma unroll
    for (int m = 0; m < 2; ++m) {
      float pm[4], psv[4];
#pragma unroll
      for (int q = 0; q < 4; ++q) {
        float v0 = acc[m][0][q] + bo[0];
        float v1 = acc[m][1][q] + bo[1];
        int r = m * 16 + lk * 4 + q;
        int tg = tS[r];
        if (tg == nbase) tgtv[rg * 32 + r] = v0;
        if (tg == nbase + 16) tgtv[rg * 32 + r] = v1;
        float mx = fmaxf(v0, v1);
#pragma unroll
        for (int d = 1; d < 16; d <<= 1) mx = fmaxf(mx, __shfl_xor(mx, d));
        float e = expf(v0 - mx) + expf(v1 - mx);
#pragma unroll
        for (int d = 1; d < 16; d <<= 1) e += __shfl_xor(e, d);
        pm[q] = mx;
        psv[q] = e;
      }
      if (lcol == 0) {
        int chunk = bid * 4 + wid;
#pragma unroll
        for (int q = 0; q < 4; ++q) {
          int r2 = rg * 32 + m * 16 + lk * 4 + q;
          pmaxA[(size_t)r2 * 1000 + chunk] = pm[q];
          psumA[(size_t)r2 * 1000 + chunk] = psv[q];
        }
      }
    }
  }
}

// one block per row; last finishing block writes the output
__global__ __launch_bounds__(256) void ce_final_kernel(
    const float* __restrict__ pmaxA, const float* __restrict__ psumA,
    const float* __restrict__ tgtv, float* __restrict__ loss,
    int* __restrict__ cectr, float* __restrict__ out) {
  int row = blockIdx.x;
  int tid = threadIdx.x;
  const float* pm = pmaxA + (size_t)row * 1000;
  const float* psv = psumA + (size_t)row * 1000;
  __shared__ float sm[256];
  float m = -INFINITY;
  for (int c = tid; c < 1000; c += 256) m = fmaxf(m, pm[c]);
  sm[tid] = m;
  __syncthreads();
  for (int off = 128; off; off >>= 1) {
    if (tid < off) sm[tid] = fmaxf(sm[tid], sm[tid + off]);
    __syncthreads();
  }
  float M = sm[0];
  __syncthreads();
  float s = 0.f;
  for (int c = tid; c < 1000; c += 256) s += psv[c] * expf(pm[c] - M);
  sm[tid] = s;
  __syncthreads();
  for (int off = 128; off; off >>= 1) {
    if (tid < off) sm[tid] += sm[tid + off];
    __syncthreads();
  }
  if (tid == 0) {
    atomicAdd(loss, (M + logf(sm[0]) - tgtv[row]) * (1.0f / 1024.0f));
    asm volatile("s_waitcnt vmcnt(0)" ::: "memory");
    int old = __hip_atomic_fetch_add(cectr, 1, __ATOMIC_ACQ_REL, __HIP_MEMORY_SCOPE_AGENT);
    if (old == 927) out[0] = AT_LOAD(loss);
  }
}

// ---------------------------------------------------------------------------
extern "C" void kernel_launch(void* const* d_in, const int* in_sizes, int n_in,
                              void* d_out, int out_size, void* d_ws, size_t ws_size,
                              hipStream_t stream) {
  (void)in_sizes; (void)n_in; (void)out_size; (void)ws_size;
  const float* feat    = (const float*)d_in[0];
  const float* caption = (const float*)d_in[1];
  const float* onehot  = (const float*)d_in[2];
  const float* w_ih1   = (const float*)d_in[4];
  const float* w_hh1   = (const float*)d_in[5];
  const float* b_ih1   = (const float*)d_in[6];
  const float* b_hh1   = (const float*)d_in[7];
  const float* w_ih2   = (const float*)d_in[8];
  const float* w_hh2   = (const float*)d_in[9];
  const float* b_ih2   = (const float*)d_in[10];
  const float* b_hh2   = (const float*)d_in[11];
  const float* w_out   = (const float*)d_in[12];
  const float* b_out   = (const float*)d_in[13];

  char* p = (char*)d_ws;
  auto alloc = [&](size_t bytes) {
    char* r = p;
    p += (bytes + 255) & ~(size_t)255;
    return r;
  };
  float* X1      = (float*)alloc(2560ull * 1024 * 4);      // 10.5 MB
  float* XW2     = (float*)alloc(29ull * 32 * 1024 * 4);   // 3.8 MB
  float* bias1   = (float*)alloc(1024 * 4);
  float* bias2   = (float*)alloc(1024 * 4);
  u32*   H1H     = (u32*)alloc(110ull * 32 * 128 * 4);     // 1.8 MB
  u32*   H2H     = (u32*)alloc(110ull * 32 * 128 * 4);     // 1.8 MB
  u16*   H2NB    = (u16*)alloc(29ull * 8192 * 2);
  float* pmaxA   = (float*)alloc(928ull * 1000 * 4);
  float* psumA   = (float*)alloc(928ull * 1000 * 4);
  float* tgtv    = (float*)alloc(928 * 4);
  float* lossacc = (float*)alloc(256);
  int*   cectr   = (int*)alloc(256);
  int*   targets = (int*)alloc(29 * 32 * 4);
  u16*   w_ih1b  = (u16*)alloc(1024ull * 4096 * 2);        // 8.4 MB
  u16*   w_ih2lb = (u16*)alloc(1024ull * 256 * 2);
  u16*   capb    = (u16*)alloc(32ull * 30 * 256 * 2);
  u16*   wPK     = (u16*)alloc(2000ull * 32 * 16 * 8 * 2); // 16.4 MB

  prep_kernel<<<11280, 256, 0, stream>>>(
      w_ih1, w_out, w_ih2, caption, onehot,
      b_ih1, b_hh1, b_ih2, b_hh2,
      w_ih1b, wPK, w_ih2lb, capb,
      bias1, bias2, H1H, H2H, lossacc, cectr, targets);
  gemms_kernel<<<624, 256, 0, stream>>>(feat, w_ih1b, bias1, X1,
                                        capb, w_ih2lb, bias2, XW2);

  RP rp;
  rp.X1 = X1; rp.XW2 = XW2; rp.bias1 = bias1; rp.bias2 = bias2;
  rp.w_hh1 = w_hh1; rp.w_ih2 = w_ih2; rp.w_hh2 = w_hh2;
  rp.H1H = H1H; rp.H2H = H2H; rp.H2NB = H2NB;
  void* args[] = {&rp};
  hipLaunchCooperativeKernel((const void*)recurrent_kernel, dim3(256), dim3(512),
                             args, 0, stream);

  logits_ce_kernel<<<250, 256, 0, stream>>>(H2NB, wPK, b_out, targets, pmaxA, psumA, tgtv);
  ce_final_kernel<<<928, 256, 0, stream>>>(pmaxA, psumA, tgtv, lossacc, cectr,
                                           (float*)d_out);
}

// Round 11
// 687.525 us; speedup vs baseline: 4.4614x; 1.0704x over previous
//
#include <hip/hip_runtime.h>
#include <hip/hip_bf16.h>
#include <math.h>

// Problem dims
#define BB 32
#define TE 80
#define FEAT 4096
#define HH 256
#define W2V 256
#define TD 30
#define VV 32000
#define G4 1024   // 4*H

typedef unsigned short u16;
typedef unsigned int u32;
using f32x4 = __attribute__((ext_vector_type(4))) float;
using bf16x8 = __attribute__((ext_vector_type(8))) short;
using f16x2 = __attribute__((ext_vector_type(2))) _Float16;

#define SENT 0xFFFFFFFFu
#define NANF 0x7FC00000u

__device__ __forceinline__ float sigm(float x) { return 1.0f / (1.0f + expf(-x)); }
__device__ __forceinline__ u16 f2bf(float f) {
  u32 u = __float_as_uint(f);
  u32 r = (u + 0x7FFFu + ((u >> 16) & 1u)) >> 16;
  return (u16)r;
}
__device__ __forceinline__ u32 packh2(float lo, float hi) {
  f16x2 v = {(_Float16)lo, (_Float16)hi};
  return __builtin_bit_cast(u32, v);
}

#define AT_LOAD(p)     __hip_atomic_load((p), __ATOMIC_RELAXED, __HIP_MEMORY_SCOPE_AGENT)
#define AT_STORE(p, v) __hip_atomic_store((p), (v), __ATOMIC_RELAXED, __HIP_MEMORY_SCOPE_AGENT)

__device__ __forceinline__ float fdot2h(f16x2 a, f16x2 b, float c) {
#if __has_builtin(__builtin_amdgcn_fdot2)
  return __builtin_amdgcn_fdot2(a, b, c, false);
#else
  return c + (float)a[0] * (float)b[0] + (float)a[1] * (float)b[1];
#endif
}

// ===========================================================================
// prep: argmax + all converts + sentinel init, one launch. 5957 blocks.
// [0,928) argmax | [928,3488) feat->bf16 | [3488,4512) w_ih1->bf16 |
// [4512,4576) w_ih2 left -> bf16 | [4576,4636) caption->bf16 |
// [4636,5076) H1H/H2H sentinel | [5076,5956) A2P sentinel | 5956 misc
// ===========================================================================
__global__ __launch_bounds__(256) void prep_kernel(
    const float* __restrict__ feat, const float* __restrict__ w_ih1,
    const float* __restrict__ w_ih2, const float* __restrict__ caption,
    const float* __restrict__ onehot,
    const float* __restrict__ b_ih1, const float* __restrict__ b_hh1,
    const float* __restrict__ b_ih2, const float* __restrict__ b_hh2,
    u16* __restrict__ featb, u16* __restrict__ w_ih1b,
    u16* __restrict__ w_ih2lb, u16* __restrict__ capb,
    float* __restrict__ bias1, float* __restrict__ bias2,
    u32* __restrict__ H1H, u32* __restrict__ H2H, u32* __restrict__ A2P,
    float* __restrict__ loss, int* __restrict__ ctrs,
    int* __restrict__ targets) {
  int blk = blockIdx.x, tid = threadIdx.x;
  if (blk < 928) {
    int k = blk;  // (s-1)*32 + b
    int s = (k >> 5) + 1, b = k & 31;
    const float* row = &onehot[((size_t)b * TD + s) * VV];
    float bv = -INFINITY;
    int bi = 0x7fffffff;
    for (int v = tid; v < VV; v += 256) {
      float x = row[v];
      if (x > bv || (x == bv && v < bi)) { bv = x; bi = v; }
    }
    __shared__ float sv[256];
    __shared__ int si[256];
    sv[tid] = bv; si[tid] = bi;
    __syncthreads();
    for (int off = 128; off; off >>= 1) {
      if (tid < off) {
        float ov = sv[tid + off]; int oi = si[tid + off];
        if (ov > sv[tid] || (ov == sv[tid] && oi < si[tid])) { sv[tid] = ov; si[tid] = oi; }
      }
      __syncthreads();
    }
    if (tid == 0) targets[k] = si[0];
  } else if (blk < 3488) {
    int i0 = (blk - 928) * 1024 + tid;
#pragma unroll
    for (int ii = 0; ii < 4; ++ii) {
      int i = i0 + ii * 256;
      float4 v = *(const float4*)&feat[(size_t)i * 4];
      *(ushort4*)&featb[(size_t)i * 4] =
          make_ushort4(f2bf(v.x), f2bf(v.y), f2bf(v.z), f2bf(v.w));
    }
  } else if (blk < 4512) {
    int i0 = (blk - 3488) * 1024 + tid;
#pragma unroll
    for (int ii = 0; ii < 4; ++ii) {
      int i = i0 + ii * 256;
      float4 v = *(const float4*)&w_ih1[(size_t)i * 4];
      *(ushort4*)&w_ih1b[(size_t)i * 4] =
          make_ushort4(f2bf(v.x), f2bf(v.y), f2bf(v.z), f2bf(v.w));
    }
  } else if (blk < 4576) {
    int i0 = (blk - 4512) * 1024 + tid;
#pragma unroll
    for (int ii = 0; ii < 4; ++ii) {
      int i = i0 + ii * 256;
      int row = i >> 6, c = (i & 63) * 4;
      float4 v = *(const float4*)&w_ih2[(size_t)row * 512 + c];
      *(ushort4*)&w_ih2lb[(size_t)row * 256 + c] =
          make_ushort4(f2bf(v.x), f2bf(v.y), f2bf(v.z), f2bf(v.w));
    }
  } else if (blk < 4636) {
    int i0 = (blk - 4576) * 1024 + tid;
#pragma unroll
    for (int ii = 0; ii < 4; ++ii) {
      int i = i0 + ii * 256;
      float4 v = *(const float4*)&caption[(size_t)i * 4];
      *(ushort4*)&capb[(size_t)i * 4] =
          make_ushort4(f2bf(v.x), f2bf(v.y), f2bf(v.z), f2bf(v.w));
    }
  } else if (blk < 5076) {
    int i = (blk - 4636) * 256 + tid;  // uint4 index < 112640
    uint4 z = {0u, 0u, 0u, 0u};
    uint4 s = {SENT, SENT, SENT, SENT};
    uint4 v = (i < 1024) ? z : s;      // slot T=0 = packed f16 zeros
    ((uint4*)H1H)[i] = v;
    ((uint4*)H2H)[i] = v;
  } else if (blk < 5956) {
    int i0 = (blk - 5076) * 1024 + tid;  // uint4 index < 901120
    uint4 s = {NANF, NANF, NANF, NANF};
#pragma unroll
    for (int ii = 0; ii < 4; ++ii) ((uint4*)A2P)[i0 + ii * 256] = s;
  } else {
    for (int i = tid; i < 1024; i += 256) {
      bias1[i] = b_ih1[i] + b_hh1[i];
      bias2[i] = b_ih2[i] + b_hh2[i];
    }
    if (tid == 0) { *loss = 0.0f; ctrs[0] = 0; ctrs[32] = 0; }
  }
}

// ===========================================================================
// Fused one-time GEMMs: blocks [0,160) = X1 MFMA GEMM (A bf16); rest XW2.
// ===========================================================================
#define GBM 128
#define GBN 128
#define GBK 64
#define LDSTR 72

__device__ void gemm_x1_body(char* smem, int bx, int by,
                             const u16* __restrict__ Ab, const u16* __restrict__ Bw,
                             const float* __restrict__ bias, float* __restrict__ C) {
  u16* As = (u16*)smem;
  u16* Bs = (u16*)(smem + 18432);
  int tid = threadIdx.x;
  int rBase = by * GBM;
  int nBase = bx * GBN;
  int lane = tid & 63, w = tid >> 6;
  int wrow = (w >> 1) * 64, wcol = (w & 1) * 64;
  int lrow = lane & 15, lk = (lane >> 4) * 8;

  f32x4 acc[4][4];
#pragma unroll
  for (int m = 0; m < 4; ++m)
#pragma unroll
    for (int n = 0; n < 4; ++n) acc[m][n] = (f32x4){0.f, 0.f, 0.f, 0.f};

  for (int k0 = 0; k0 < FEAT; k0 += GBK) {
#pragma unroll
    for (int i = 0; i < 4; ++i) {
      int f = i * 256 + tid;  // uint4 id 0..1023
      int r = f >> 3, c8 = f & 7;
      *(uint4*)&As[r * LDSTR + c8 * 8] =
          *(const uint4*)&Ab[(size_t)(rBase + r) * FEAT + k0 + c8 * 8];
    }
#pragma unroll
    for (int i = 0; i < 4; ++i) {
      int f = i * 256 + tid;
      int r = f >> 3, c8 = f & 7;
      *(uint4*)&Bs[r * LDSTR + c8 * 8] =
          *(const uint4*)&Bw[(size_t)(nBase + r) * FEAT + k0 + c8 * 8];
    }
    __syncthreads();
#pragma unroll
    for (int s2 = 0; s2 < 2; ++s2) {
      bf16x8 af[4], bfr[4];
#pragma unroll
      for (int m = 0; m < 4; ++m)
        af[m] = *(const bf16x8*)&As[(wrow + m * 16 + lrow) * LDSTR + s2 * 32 + lk];
#pragma unroll
      for (int n = 0; n < 4; ++n)
        bfr[n] = *(const bf16x8*)&Bs[(wcol + n * 16 + lrow) * LDSTR + s2 * 32 + lk];
#pragma unroll
      for (int m = 0; m < 4; ++m)
#pragma unroll
        for (int n = 0; n < 4; ++n)
          acc[m][n] = __builtin_amdgcn_mfma_f32_16x16x32_bf16(
              af[m], bfr[n], acc[m][n], 0, 0, 0);
    }
    __syncthreads();
  }
  int orow = (lane >> 4) * 4;
  int ocol = lane & 15;
#pragma unroll
  for (int m = 0; m < 4; ++m)
#pragma unroll
    for (int n = 0; n < 4; ++n) {
      int cidx = nBase + wcol + n * 16 + ocol;
      float bv = bias[cidx];
#pragma unroll
      for (int q = 0; q < 4; ++q) {
        int r = rBase + wrow + m * 16 + orow + q;
        C[(size_t)r * G4 + cidx] = acc[m][n][q] + bv;
      }
    }
}

__device__ void xw2_body(char* smem, int nb, int t,
                         const u16* __restrict__ capb, const u16* __restrict__ w_ih2lb,
                         const float* __restrict__ bias2, float* __restrict__ XW2) {
  u16* As = (u16*)smem;
  u16* Bs = (u16*)(smem + 16896);
  int tid = threadIdx.x;
  int nBase = nb * 64;
#pragma unroll
  for (int it = 0; it < 4; ++it) {
    int i = it * 256 + tid;
    int r = i >> 5, c8 = i & 31;
    *(uint4*)&As[r * 264 + c8 * 8] =
        *(const uint4*)&capb[((size_t)r * TD + t) * 256 + c8 * 8];
  }
#pragma unroll
  for (int it = 0; it < 8; ++it) {
    int i = it * 256 + tid;
    int r = i >> 5, c8 = i & 31;
    *(uint4*)&Bs[r * 264 + c8 * 8] =
        *(const uint4*)&w_ih2lb[(size_t)(nBase + r) * 256 + c8 * 8];
  }
  __syncthreads();
  int lane = tid & 63, w = tid >> 6;
  int lrow = lane & 15, lk = (lane >> 4) * 8;
  f32x4 acc[2];
  acc[0] = (f32x4){0.f, 0.f, 0.f, 0.f};
  acc[1] = (f32x4){0.f, 0.f, 0.f, 0.f};
#pragma unroll
  for (int ks = 0; ks < 8; ++ks) {
    bf16x8 bfr = *(const bf16x8*)&Bs[(w * 16 + lrow) * 264 + ks * 32 + lk];
#pragma unroll
    for (int m = 0; m < 2; ++m) {
      bf16x8 af = *(const bf16x8*)&As[(m * 16 + lrow) * 264 + ks * 32 + lk];
      acc[m] = __builtin_amdgcn_mfma_f32_16x16x32_bf16(af, bfr, acc[m], 0, 0, 0);
    }
  }
  int col = nBase + w * 16 + (lane & 15);
  float bv = bias2[col];
  int orow = (lane >> 4) * 4;
#pragma unroll
  for (int m = 0; m < 2; ++m)
#pragma unroll
    for (int q = 0; q < 4; ++q) {
      int bb = m * 16 + orow + q;
      XW2[((size_t)t * 32 + bb) * G4 + col] = acc[m][q] + bv;
    }
}

__global__ __launch_bounds__(256) void gemms_kernel(
    const u16* __restrict__ featb, const u16* __restrict__ w_ih1b,
    const float* __restrict__ bias1, float* __restrict__ X1,
    const u16* __restrict__ capb, const u16* __restrict__ w_ih2lb,
    const float* __restrict__ bias2, float* __restrict__ XW2) {
  __shared__ __align__(16) char smem[50688];
  int blk = blockIdx.x;
  if (blk < 160) {
    gemm_x1_body(smem, blk & 7, blk >> 3, featb, w_ih1b, bias1, X1);
  } else {
    int k = blk - 160;
    xw2_body(smem, k & 15, k >> 4, capb, w_ih2lb, bias2, XW2);
  }
}

// ===========================================================================
// Persistent recurrent kernel. 256 blocks x 512 threads (cooperative).
// L1 blocks [0,128): h1 chain + a2p = w_ih2r.h1[T] partial (wA+wB = 128 regs,
//   spill tolerated — L1 runs ahead of L2B). Publishes h1[T+1] and a2p[T].
// L2B blocks [128,256): h2 chain: gates2 = a2p + wC.h2 + x2. Only wC in regs
//   (64 f16x2, no spill). encL history + attention. 2 syncs/encoder-step.
// Self-validating sentinel exchange (f16-NaN pair / f32-NaN): one LLC round
// trip per chain step; h2 poll is pure spin (critical path).
// ===========================================================================
struct RP {
  const float *X1, *XW2, *bias1, *bias2;
  const float *w_hh1, *w_ih2, *w_hh2;
  u32* H1H;     // [110][32][128] packed f16x2 of h1[T]
  u32* H2H;     // [110][32][128] packed f16x2 of h2[U]
  u32* A2P;     // [110][32][1024] f32 bits: w_ih2r . h1[T]
  u16* H2NB;    // [29][32][256] bf16 decoder h2n
};

__global__ __launch_bounds__(512, 1) void recurrent_kernel(RP p) {
  __shared__ float encL[TE][257];             // 82 KB (L2B)
  __shared__ __align__(16) f16x2 hS[128];
  __shared__ float tmp2[256];
  __shared__ float gb[256];
  __shared__ float a2pS[256];
  __shared__ float hnew[64];
  __shared__ float sc[80];
  __shared__ float red[4];
  int bid = blockIdx.x, tid = threadIdx.x;
  bool isL1 = bid < 128;
  int lb = isL1 ? bid : bid - 128;
  int b = lb >> 2, q = lb & 3;
  int r2 = tid >> 1, half = tid & 1;
  int g = r2 >> 6, jj = r2 & 63;
  int grow = (g << 8) + (q << 6) + jj;
  int jf = (q << 6) + tid;                    // valid for tid<64

  if (isL1) {
    f16x2 wA[64], wB[64];
    {
      const float4* sA = (const float4*)(p.w_hh1 + (size_t)grow * 256 + half * 128);
      const float4* sB = (const float4*)(p.w_ih2 + (size_t)grow * 512 + 256 + half * 128);
#pragma unroll
      for (int k = 0; k < 32; ++k) {
        float4 v = sA[k];
        wA[k * 2 + 0] = f16x2{(_Float16)v.x, (_Float16)v.y};
        wA[k * 2 + 1] = f16x2{(_Float16)v.z, (_Float16)v.w};
        float4 u = sB[k];
        wB[k * 2 + 0] = f16x2{(_Float16)u.x, (_Float16)u.y};
        wB[k * 2 + 1] = f16x2{(_Float16)u.z, (_Float16)u.w};
      }
    }
    float c1 = 0.f;
    float b1v0 = 0, b1v1 = 0, b1v2 = 0, b1v3 = 0;
    if (tid < 64) {
      b1v0 = p.bias1[jf]; b1v1 = p.bias1[256 + jf];
      b1v2 = p.bias1[512 + jf]; b1v3 = p.bias1[768 + jf];
    }
    for (int T = 0; T <= 109; ++T) {
      float x0 = b1v0, x1 = b1v1, x2 = b1v2, x3 = b1v3;
      if (tid < 64 && T < TE) {
        const float* xb = &p.X1[((size_t)b * TE + T) * G4 + jf];
        x0 = xb[0]; x1 = xb[256]; x2 = xb[512]; x3 = xb[768];
      }
      if (tid < 128) {
        const u32* src = &p.H1H[((size_t)T * 32 + b) * 128 + tid];
        u32 v = AT_LOAD(src);
        int gd = 0;
        while (v == SENT && ++gd < (1 << 24)) {
          __builtin_amdgcn_s_sleep(1);
          v = AT_LOAD(src);
        }
        hS[tid] = __builtin_bit_cast(f16x2, v);
      }
      __syncthreads();  // S1
      float a1 = 0.f, a2 = 0.f;
      {
        const uint4* hv = ((const uint4*)hS) + half * 16;
#pragma unroll
        for (int k = 0; k < 16; ++k) {
          uint4 uu = hv[k];
          f16x2 e0 = __builtin_bit_cast(f16x2, uu.x), e1 = __builtin_bit_cast(f16x2, uu.y);
          f16x2 e2 = __builtin_bit_cast(f16x2, uu.z), e3 = __builtin_bit_cast(f16x2, uu.w);
          a1 = fdot2h(e0, wA[k * 4 + 0], a1);
          a2 = fdot2h(e0, wB[k * 4 + 0], a2);
          a1 = fdot2h(e1, wA[k * 4 + 1], a1);
          a2 = fdot2h(e1, wB[k * 4 + 1], a2);
          a1 = fdot2h(e2, wA[k * 4 + 2], a1);
          a2 = fdot2h(e2, wB[k * 4 + 2], a2);
          a1 = fdot2h(e3, wA[k * 4 + 3], a1);
          a2 = fdot2h(e3, wB[k * 4 + 3], a2);
        }
      }
      a1 += __shfl_xor(a1, 1);
      a2 += __shfl_xor(a2, 1);
      if (half == 0) {
        gb[r2] = a1;
        if (T >= 1)
          AT_STORE(&p.A2P[((size_t)T * 32 + b) * 1024 + grow], __float_as_uint(a2));
      }
      __syncthreads();  // S2
      if (T <= 108) {
        if (tid < 64) {
          float gi = gb[tid] + x0;
          float gf = gb[64 + tid] + x1;
          float gG = gb[128 + tid] + x2;
          float go = gb[192 + tid] + x3;
          c1 = sigm(gf) * c1 + sigm(gi) * tanhf(gG);
          hnew[tid] = sigm(go) * tanhf(c1);
        }
        if (tid < 32) {  // same wave as hnew writers -> ordered
          u32 pk = packh2(hnew[2 * tid], hnew[2 * tid + 1]);
          AT_STORE(&p.H1H[((size_t)(T + 1) * 32 + b) * 128 + (q << 5) + tid], pk);
        }
      }
    }
  } else {
    f16x2 wC[64];
    {
      const float4* sC = (const float4*)(p.w_hh2 + (size_t)grow * 256 + half * 128);
#pragma unroll
      for (int k = 0; k < 32; ++k) {
        float4 u = sC[k];
        wC[k * 2 + 0] = f16x2{(_Float16)u.x, (_Float16)u.y};
        wC[k * 2 + 1] = f16x2{(_Float16)u.z, (_Float16)u.w};
      }
    }
    float c2 = 0.f;
    float b2v0 = 0, b2v1 = 0, b2v2 = 0, b2v3 = 0;
    if (tid < 64) {
      b2v0 = p.bias2[jf]; b2v1 = p.bias2[256 + jf];
      b2v2 = p.bias2[512 + jf]; b2v3 = p.bias2[768 + jf];
    }
    for (int U = 1; U <= 109; ++U) {
      float x0 = b2v0, x1 = b2v1, x2 = b2v2, x3 = b2v3;
      if (tid < 64 && U >= 81) {
        const float* xb = &p.XW2[((size_t)(U - 81) * 32 + b) * G4 + jf];
        x0 = xb[0]; x1 = xb[256]; x2 = xb[512]; x3 = xb[768];
      }
      if (tid < 128) {
        const u32* src = &p.H2H[((size_t)(U - 1) * 32 + b) * 128 + tid];
        u32 v = AT_LOAD(src);
        int gd = 0;
        while (v == SENT && ++gd < (1 << 26)) v = AT_LOAD(src);  // pure spin
        f16x2 hp = __builtin_bit_cast(f16x2, v);
        hS[tid] = hp;
        tmp2[2 * tid] = (float)hp[0];
        tmp2[2 * tid + 1] = (float)hp[1];
      } else if (tid < 384) {
        int rr = tid - 128;
        int growp = ((rr >> 6) << 8) + (q << 6) + (rr & 63);
        const u32* src = &p.A2P[((size_t)U * 32 + b) * 1024 + growp];
        u32 v = AT_LOAD(src);
        int gd = 0;
        while (v == NANF && ++gd < (1 << 24)) {
          __builtin_amdgcn_s_sleep(1);
          v = AT_LOAD(src);
        }
        a2pS[rr] = __uint_as_float(v);
      }
      __syncthreads();  // S1
      float a2p0 = 0, a2p1 = 0, a2p2 = 0, a2p3 = 0;
      if (tid < 64) {
        a2p0 = a2pS[tid]; a2p1 = a2pS[64 + tid];
        a2p2 = a2pS[128 + tid]; a2p3 = a2pS[192 + tid];
      }
      if (U <= 81) {
        if (U >= 2 && tid < 256) encL[U - 2][tid] = tmp2[tid];
      } else {
        // attention: q-vec = tmp2 (h2n[s-1]); parallel softmax; ctx -> hS
        float a = 0.f;
        if (tid < TE) {
          const float* e = &encL[tid][0];
#pragma unroll 8
          for (int k2 = 0; k2 < 256; ++k2) a += e[k2] * tmp2[k2];
        }
        float av = (tid < TE) ? a : -INFINITY;
#pragma unroll
        for (int d = 32; d; d >>= 1) av = fmaxf(av, __shfl_xor(av, d));
        if (tid == 0) red[0] = av;
        if (tid == 64) red[1] = av;
        __syncthreads();
        float m = fmaxf(red[0], red[1]);
        float e2 = (tid < TE) ? expf(a - m) : 0.f;
        float sv = e2;
#pragma unroll
        for (int d = 32; d; d >>= 1) sv += __shfl_xor(sv, d);
        if (tid == 0) red[2] = sv;
        if (tid == 64) red[3] = sv;
        __syncthreads();
        float inv = 1.0f / (red[2] + red[3]);
        if (tid < TE) sc[tid] = e2 * inv;
        __syncthreads();
        if (tid < 256) {
          float acc = 0.f;
          for (int t2 = 0; t2 < TE; ++t2) acc += sc[t2] * encL[t2][tid];
          tmp2[tid] = acc;
        }
        __syncthreads();
        if (tid < 128)
          hS[tid] = f16x2{(_Float16)tmp2[2 * tid], (_Float16)tmp2[2 * tid + 1]};
        __syncthreads();
      }
      float a2 = 0.f;
      {
        const uint4* hv = ((const uint4*)hS) + half * 16;
#pragma unroll
        for (int k = 0; k < 16; ++k) {
          uint4 uu = hv[k];
          a2 = fdot2h(__builtin_bit_cast(f16x2, uu.x), wC[k * 4 + 0], a2);
          a2 = fdot2h(__builtin_bit_cast(f16x2, uu.y), wC[k * 4 + 1], a2);
          a2 = fdot2h(__builtin_bit_cast(f16x2, uu.z), wC[k * 4 + 2], a2);
          a2 = fdot2h(__builtin_bit_cast(f16x2, uu.w), wC[k * 4 + 3], a2);
        }
      }
      a2 += __shfl_xor(a2, 1);
      if (half == 0) gb[r2] = a2;
      __syncthreads();  // S6
      if (tid < 64) {
        float gi = gb[tid] + a2p0 + x0;
        float gf = gb[64 + tid] + a2p1 + x1;
        float gG = gb[128 + tid] + a2p2 + x2;
        float go = gb[192 + tid] + a2p3 + x3;
        c2 = sigm(gf) * c2 + sigm(gi) * tanhf(gG);
        float h = sigm(go) * tanhf(c2);
        hnew[tid] = h;
        if (U >= 81)
          p.H2NB[((size_t)(U - 81) * 32 + b) * 256 + jf] = f2bf(h);
      }
      if (tid < 32) {  // same wave as hnew writers
        u32 pk = packh2(hnew[2 * tid], hnew[2 * tid + 1]);
        AT_STORE(&p.H2H[((size_t)U * 32 + b) * 128 + (q << 5) + tid], pk);
      }
    }
  }
}

// ===========================================================================
// Fused logits + CE partials + final reduce (250 co-resident blocks).
// Stage B from w_out f32 (convert inline, MFMA layout). Partials via
// agent-scope stores; counter barrier; each block reduces 4 rows; last
// finisher writes d_out.
// ===========================================================================
__global__ __launch_bounds__(256, 1) void logits_final_kernel(
    const u16* __restrict__ H2NB, const float* __restrict__ w_out,
    const float* __restrict__ b_out, const int* __restrict__ targets,
    u32* __restrict__ pmaxA, u32* __restrict__ psumA, u32* __restrict__ tgtv,
    float* __restrict__ loss, int* __restrict__ ctrs, float* __restrict__ out) {
  __shared__ __align__(16) u16 bS[32768];
  __shared__ __align__(16) u16 aS[32 * 264];
  __shared__ int tS[32];
  __shared__ float sm[256];
  int tid = threadIdx.x, bid = blockIdx.x;
  // stage B: 128 n-rows x 256 k, f32 -> bf16 MFMA layout
#pragma unroll
  for (int it = 0; it < 16; ++it) {
    int id = it * 256 + tid;           // nt*512 + rr*32 + kg
    int nt = id >> 9, rr = (id >> 5) & 15, kg = id & 31;
    int n = bid * 128 + nt * 16 + rr;
    const float* src = &w_out[(size_t)n * 256 + kg * 8];
    float4 v0 = *(const float4*)src;
    float4 v1 = *(const float4*)(src + 4);
    u16* dst = &bS[(size_t)((nt * 32 + kg) * 16 + rr) * 8];
    *(ushort4*)dst = make_ushort4(f2bf(v0.x), f2bf(v0.y), f2bf(v0.z), f2bf(v0.w));
    *(ushort4*)(dst + 4) = make_ushort4(f2bf(v1.x), f2bf(v1.y), f2bf(v1.z), f2bf(v1.w));
  }
  int wid = tid >> 6, lane = tid & 63, lcol = lane & 15, lk = lane >> 4;
  float bo[2];
#pragma unroll
  for (int n = 0; n < 2; ++n) bo[n] = b_out[(bid * 8 + wid * 2 + n) * 16 + lcol];

  for (int rg = 0; rg < 29; ++rg) {
    __syncthreads();
    for (int i = tid; i < 1024; i += 256) {
      int r = i >> 5, c8 = i & 31;
      *(uint4*)&aS[r * 264 + c8 * 8] =
          *(const uint4*)&H2NB[(size_t)rg * 8192 + r * 256 + c8 * 8];
    }
    if (tid < 32) tS[tid] = targets[rg * 32 + tid];
    __syncthreads();
    f32x4 acc[2][2];
#pragma unroll
    for (int m = 0; m < 2; ++m)
#pragma unroll
      for (int n = 0; n < 2; ++n) acc[m][n] = (f32x4){0.f, 0.f, 0.f, 0.f};
#pragma unroll
    for (int ks = 0; ks < 8; ++ks) {
      bf16x8 a0 = *(const bf16x8*)&aS[lcol * 264 + ks * 32 + lk * 8];
      bf16x8 a1 = *(const bf16x8*)&aS[(16 + lcol) * 264 + ks * 32 + lk * 8];
      bf16x8 b0 = *(const bf16x8*)&bS[(wid * 2) * 4096 + ((ks * 4 + lk) * 16 + lcol) * 8];
      bf16x8 b1 = *(const bf16x8*)&bS[(wid * 2 + 1) * 4096 + ((ks * 4 + lk) * 16 + lcol) * 8];
      acc[0][0] = __builtin_amdgcn_mfma_f32_16x16x32_bf16(a0, b0, acc[0][0], 0, 0, 0);
      acc[0][1] = __builtin_amdgcn_mfma_f32_16x16x32_bf16(a0, b1, acc[0][1], 0, 0, 0);
      acc[1][0] = __builtin_amdgcn_mfma_f32_16x16x32_bf16(a1, b0, acc[1][0], 0, 0, 0);
      acc[1][1] = __builtin_amdgcn_mfma_f32_16x16x32_bf16(a1, b1, acc[1][1], 0, 0, 0);
    }
    int nbase = (bid * 8 + wid * 2) * 16 + lcol;
#pragma unroll
    for (int m = 0; m < 2; ++m) {
      float pm[4], psv[4];
#pragma unroll
      for (int qq = 0; qq < 4; ++qq) {
        float v0 = acc[m][0][qq] + bo[0];
        float v1 = acc[m][1][qq] + bo[1];
        int r = m * 16 + lk * 4 + qq;
        int tg = tS[r];
        if (tg == nbase) AT_STORE(&tgtv[rg * 32 + r], __float_as_uint(v0));
        if (tg == nbase + 16) AT_STORE(&tgtv[rg * 32 + r], __float_as_uint(v1));
        float mx = fmaxf(v0, v1);
#pragma unroll
        for (int d = 1; d < 16; d <<= 1) mx = fmaxf(mx, __shfl_xor(mx, d));
        float e = expf(v0 - mx) + expf(v1 - mx);
#pragma unroll
        for (int d = 1; d < 16; d <<= 1) e += __shfl_xor(e, d);
        pm[qq] = mx;
        psv[qq] = e;
      }
      if (lcol == 0) {
        int chunk = bid * 4 + wid;
#pragma unroll
        for (int qq = 0; qq < 4; ++qq) {
          int r2 = rg * 32 + m * 16 + lk * 4 + qq;
          AT_STORE(&pmaxA[(size_t)r2 * 1000 + chunk], __float_as_uint(pm[qq]));
          AT_STORE(&psumA[(size_t)r2 * 1000 + chunk], __float_as_uint(psv[qq]));
        }
      }
    }
  }
  // ---- barrier among the 250 co-resident blocks ----
  asm volatile("s_waitcnt vmcnt(0)" ::: "memory");
  __syncthreads();
  if (tid == 0) {
    __hip_atomic_fetch_add(&ctrs[0], 1, __ATOMIC_RELEASE, __HIP_MEMORY_SCOPE_AGENT);
    int gd = 0;
    while (__hip_atomic_load(&ctrs[0], __ATOMIC_ACQUIRE, __HIP_MEMORY_SCOPE_AGENT) < 250 &&
           ++gd < (1 << 26))
      __builtin_amdgcn_s_sleep(2);
  }
  __syncthreads();
  // ---- final: 4 rows per block ----
#pragma unroll
  for (int k = 0; k < 4; ++k) {
    int row = bid * 4 + k;
    if (row < 928) {
      const u32* pm = pmaxA + (size_t)row * 1000;
      const u32* psv = psumA + (size_t)row * 1000;
      float m = -INFINITY;
      for (int c = tid; c < 1000; c += 256) m = fmaxf(m, __uint_as_float(AT_LOAD(&pm[c])));
      sm[tid] = m;
      __syncthreads();
      for (int off = 128; off; off >>= 1) {
        if (tid < off) sm[tid] = fmaxf(sm[tid], sm[tid + off]);
        __syncthreads();
      }
      float M = sm[0];
      __syncthreads();
      float s = 0.f;
      for (int c = tid; c < 1000; c += 256)
        s += __uint_as_float(AT_LOAD(&psv[c])) * expf(__uint_as_float(AT_LOAD(&pm[c])) - M);
      sm[tid] = s;
      __syncthreads();
      for (int off = 128; off; off >>= 1) {
        if (tid < off) sm[tid] += sm[tid + off];
        __syncthreads();
      }
      if (tid == 0) {
        float tv = __uint_as_float(AT_LOAD(&tgtv[row]));
        atomicAdd(loss, (M + logf(sm[0]) - tv) * (1.0f / 1024.0f));
      }
      __syncthreads();
    }
  }
  asm volatile("s_waitcnt vmcnt(0)" ::: "memory");
  if (tid == 0) {
    int old = __hip_atomic_fetch_add(&ctrs[32], 1, __ATOMIC_ACQ_REL, __HIP_MEMORY_SCOPE_AGENT);
    if (old == 249) out[0] = __uint_as_float(AT_LOAD((u32*)loss));
  }
}

// ---------------------------------------------------------------------------
extern "C" void kernel_launch(void* const* d_in, const int* in_sizes, int n_in,
                              void* d_out, int out_size, void* d_ws, size_t ws_size,
                              hipStream_t stream) {
  (void)in_sizes; (void)n_in; (void)out_size; (void)ws_size;
  const float* feat    = (const float*)d_in[0];
  const float* caption = (const float*)d_in[1];
  const float* onehot  = (const float*)d_in[2];
  const float* w_ih1   = (const float*)d_in[4];
  const float* w_hh1   = (const float*)d_in[5];
  const float* b_ih1   = (const float*)d_in[6];
  const float* b_hh1   = (const float*)d_in[7];
  const float* w_ih2   = (const float*)d_in[8];
  const float* w_hh2   = (const float*)d_in[9];
  const float* b_ih2   = (const float*)d_in[10];
  const float* b_hh2   = (const float*)d_in[11];
  const float* w_out   = (const float*)d_in[12];
  const float* b_out   = (const float*)d_in[13];

  char* p = (char*)d_ws;
  auto alloc = [&](size_t bytes) {
    char* r = p;
    p += (bytes + 255) & ~(size_t)255;
    return r;
  };
  float* X1      = (float*)alloc(2560ull * 1024 * 4);      // 10.5 MB
  float* XW2     = (float*)alloc(29ull * 32 * 1024 * 4);   // 3.8 MB
  float* bias1   = (float*)alloc(1024 * 4);
  float* bias2   = (float*)alloc(1024 * 4);
  u32*   H1H     = (u32*)alloc(110ull * 32 * 128 * 4);     // 1.8 MB
  u32*   H2H     = (u32*)alloc(110ull * 32 * 128 * 4);     // 1.8 MB
  u32*   A2P     = (u32*)alloc(110ull * 32 * 1024 * 4);    // 14.4 MB
  u16*   H2NB    = (u16*)alloc(29ull * 8192 * 2);
  u32*   pmaxA   = (u32*)alloc(928ull * 1000 * 4);
  u32*   psumA   = (u32*)alloc(928ull * 1000 * 4);
  u32*   tgtv    = (u32*)alloc(928 * 4);
  float* lossacc = (float*)alloc(256);
  int*   ctrs    = (int*)alloc(256);
  int*   targets = (int*)alloc(29 * 32 * 4);
  u16*   featb   = (u16*)alloc(2560ull * 4096 * 2);        // 21 MB
  u16*   w_ih1b  = (u16*)alloc(1024ull * 4096 * 2);        // 8.4 MB
  u16*   w_ih2lb = (u16*)alloc(1024ull * 256 * 2);
  u16*   capb    = (u16*)alloc(32ull * 30 * 256 * 2);

  prep_kernel<<<5957, 256, 0, stream>>>(
      feat, w_ih1, w_ih2, caption, onehot,
      b_ih1, b_hh1, b_ih2, b_hh2,
      featb, w_ih1b, w_ih2lb, capb,
      bias1, bias2, H1H, H2H, A2P, lossacc, ctrs, targets);
  gemms_kernel<<<624, 256, 0, stream>>>(featb, w_ih1b, bias1, X1,
                                        capb, w_ih2lb, bias2, XW2);

  RP rp;
  rp.X1 = X1; rp.XW2 = XW2; rp.bias1 = bias1; rp.bias2 = bias2;
  rp.w_hh1 = w_hh1; rp.w_ih2 = w_ih2; rp.w_hh2 = w_hh2;
  rp.H1H = H1H; rp.H2H = H2H; rp.A2P = A2P; rp.H2NB = H2NB;
  void* args[] = {&rp};
  hipLaunchCooperativeKernel((const void*)recurrent_kernel, dim3(256), dim3(512),
                             args, 0, stream);

  logits_final_kernel<<<250, 256, 0, stream>>>(H2NB, w_out, b_out, targets,
                                               pmaxA, psumA, tgtv, lossacc, ctrs,
                                               (float*)d_out);
}